// Round 5
// baseline (441.657 us; speedup 1.0000x reference)
//
#include <hip/hip_runtime.h>
#include <hip/hip_bf16.h>
#include <math.h>
#include <stdint.h>

// B=8, P1=256 -> T=512 concat rows, C=1024, H=4096
#define TB_ 8
#define TT_ 512
#define TC_ 1024
// wkv chunked scan: 32 chunks of 16 steps
#define WKV_NCH 32
#define WKV_L 16

typedef __attribute__((ext_vector_type(8))) short bf16x8;
typedef __attribute__((ext_vector_type(4))) short s16x4;
typedef __attribute__((ext_vector_type(4))) float f32x4;

__device__ __forceinline__ float b2f(short u) {
  union { unsigned int i; float f; } x;
  x.i = ((unsigned int)(unsigned short)u) << 16;
  return x.f;
}
__device__ __forceinline__ short f2b(float f) {
  __hip_bfloat16 h = __float2bfloat16(f);  // RNE
  return __builtin_bit_cast(short, h);
}
__device__ __forceinline__ float sigm(float x) { return 1.0f / (1.0f + expf(-x)); }

// LIF over 4 identical inputs (closed form of the reference scan), TAU=2, VTH=1
__device__ __forceinline__ float lif4(float a) {
  float v = 0.0f, acc = 0.0f;
#pragma unroll
  for (int i = 0; i < 4; ++i) {
    v += (a - v) * 0.5f;
    float s = (v >= 1.0f) ? 1.0f : 0.0f;
    acc += s;
    v *= (1.0f - s);
  }
  return acc * 0.25f;
}

__device__ __forceinline__ void gload16(const void* g, void* l) {
  __builtin_amdgcn_global_load_lds(
      (__attribute__((address_space(1))) void*)(g),
      (__attribute__((address_space(3))) void*)(l), 16, 0, 0);
}

// ---------------- elementwise kernels ----------------

__global__ __launch_bounds__(256) void build_xc(const float* __restrict__ x,
                                                const float* __restrict__ rt,
                                                float* __restrict__ xc) {
  int i = blockIdx.x * 256 + threadIdx.x;  // float4 index over B*T*C/4
  int c4 = i & 255;
  int t = (i >> 8) & 511;
  int b = i >> 17;
  float4 v;
  if (t < 256)
    v = ((const float4*)x)[(b * 256 + t) * 256 + c4];
  else
    v = ((const float4*)rt)[(t - 256) * 256 + c4];
  ((float4*)xc)[i] = v;
}

// LayerNorm each row (C=1024 f32) -> bf16. One 256-thread block per row.
__global__ __launch_bounds__(256) void ln_rows_b(const float* __restrict__ src,
                                                 short* __restrict__ dst) {
  __shared__ float red[256];
  int64_t row = blockIdx.x;
  float4 v = ((const float4*)(src + row * TC_))[threadIdx.x];
  red[threadIdx.x] = v.x + v.y + v.z + v.w;
  __syncthreads();
  for (int off = 128; off > 0; off >>= 1) {
    if (threadIdx.x < off) red[threadIdx.x] += red[threadIdx.x + off];
    __syncthreads();
  }
  float mean = red[0] * (1.0f / 1024.0f);
  __syncthreads();
  float dx = v.x - mean, dy = v.y - mean, dz = v.z - mean, dw = v.w - mean;
  red[threadIdx.x] = dx * dx + dy * dy + dz * dz + dw * dw;
  __syncthreads();
  for (int off = 128; off > 0; off >>= 1) {
    if (threadIdx.x < off) red[threadIdx.x] += red[threadIdx.x + off];
    __syncthreads();
  }
  float rs = 1.0f / sqrtf(red[0] * (1.0f / 1024.0f) + 1e-6f);
  s16x4 o;
  o.x = f2b(dx * rs); o.y = f2b(dy * rs); o.z = f2b(dz * rs); o.w = f2b(dw * rs);
  *(s16x4*)(dst + row * TC_ + threadIdx.x * 4) = o;
}

// time-mix blends from bf16 LN. 8 elems/thread; i over B*T*C/8.
__global__ __launch_bounds__(256) void mix3_b(const short* __restrict__ ln,
                                              const float* __restrict__ tk,
                                              const float* __restrict__ tv,
                                              const float* __restrict__ tr,
                                              short* __restrict__ xk,
                                              short* __restrict__ xv,
                                              short* __restrict__ xr) {
  int i = blockIdx.x * 256 + threadIdx.x;  // short8 index
  int c8 = i & 127;
  int t = (i >> 7) & 511;
  bf16x8 h = *(const bf16x8*)(ln + (int64_t)i * 8);
  bf16x8 s = {};
  if (t > 0) s = *(const bf16x8*)(ln + (int64_t)(i - 128) * 8);
  bf16x8 ok, ov, orr;
#pragma unroll
  for (int e = 0; e < 8; ++e) {
    float hf = b2f(h[e]), sf = b2f(s[e]);
    int c = c8 * 8 + e;
    float mk = tk[c], mv = tv[c], mr = tr[c];
    ok[e] = f2b(hf * mk + sf * (1.0f - mk));
    ov[e] = f2b(hf * mv + sf * (1.0f - mv));
    orr[e] = f2b(hf * mr + sf * (1.0f - mr));
  }
  *(bf16x8*)(xk + (int64_t)i * 8) = ok;
  *(bf16x8*)(xv + (int64_t)i * 8) = ov;
  *(bf16x8*)(xr + (int64_t)i * 8) = orr;
}

__global__ __launch_bounds__(256) void mix2_b(const short* __restrict__ ln,
                                              const float* __restrict__ tk,
                                              const float* __restrict__ tr,
                                              short* __restrict__ xk,
                                              short* __restrict__ xr) {
  int i = blockIdx.x * 256 + threadIdx.x;
  int c8 = i & 127;
  int t = (i >> 7) & 511;
  bf16x8 h = *(const bf16x8*)(ln + (int64_t)i * 8);
  bf16x8 s = {};
  if (t > 0) s = *(const bf16x8*)(ln + (int64_t)(i - 128) * 8);
  bf16x8 ok, orr;
#pragma unroll
  for (int e = 0; e < 8; ++e) {
    float hf = b2f(h[e]), sf = b2f(s[e]);
    int c = c8 * 8 + e;
    float mk = tk[c], mr = tr[c];
    ok[e] = f2b(hf * mk + sf * (1.0f - mk));
    orr[e] = f2b(hf * mr + sf * (1.0f - mr));
  }
  *(bf16x8*)(xk + (int64_t)i * 8) = ok;
  *(bf16x8*)(xr + (int64_t)i * 8) = orr;
}

// f32 -> bf16, 8 elems/thread
__global__ __launch_bounds__(256) void cvt_b(const float* __restrict__ src,
                                             short* __restrict__ dst) {
  int64_t i = (int64_t)(blockIdx.x * 256 + threadIdx.x) * 8;
  float4 a = *(const float4*)(src + i);
  float4 b = *(const float4*)(src + i + 4);
  bf16x8 o;
  o[0] = f2b(a.x); o[1] = f2b(a.y); o[2] = f2b(a.z); o[3] = f2b(a.w);
  o[4] = f2b(b.x); o[5] = f2b(b.y); o[6] = f2b(b.z); o[7] = f2b(b.w);
  *(bf16x8*)(dst + i) = o;
}

// rtok rows (per b: rows 256..511 of XC) f32 -> bf16 contiguous (B,256,C)
__global__ __launch_bounds__(256) void cvt_rtok(const float* __restrict__ xc,
                                                short* __restrict__ dst) {
  int i = blockIdx.x * 256 + threadIdx.x;  // short8 idx
  int b = i >> 15;
  int rem = i & 32767;
  const float* s = xc + (int64_t)b * 524288 + 262144 + (int64_t)rem * 8;
  float4 a = *(const float4*)s;
  float4 c = *(const float4*)(s + 4);
  bf16x8 o;
  o[0] = f2b(a.x); o[1] = f2b(a.y); o[2] = f2b(a.z); o[3] = f2b(a.w);
  o[4] = f2b(c.x); o[5] = f2b(c.y); o[6] = f2b(c.z); o[7] = f2b(c.w);
  *(bf16x8*)(dst + (int64_t)i * 8) = o;
}

// ---------------- wkv chunked parallel scan ----------------
__global__ __launch_bounds__(256) void wkv_p1(const float* __restrict__ td,
                                              const short* __restrict__ K,
                                              const short* __restrict__ V,
                                              float* __restrict__ Ca,
                                              float* __restrict__ Da,
                                              float* __restrict__ Qa) {
  int bx = blockIdx.x;  // [ch:5][b:3][cg:2]
  int ch = bx >> 5;
  int b = (bx >> 2) & 7;
  int c = (bx & 3) * 256 + threadIdx.x;
  float w = -expf(td[c]);
  float aa = 0.0f, bb = 0.0f, pp = -1e38f;
  int64_t base = ((int64_t)b * TT_ + ch * WKV_L) * TC_ + c;
#pragma unroll
  for (int t = 0; t < WKV_L; ++t) {
    int64_t o = base + (int64_t)t * TC_;
    float kt = b2f(K[o]), vt = b2f(V[o]);
    float ww2 = pp + w;
    float p2 = fmaxf(ww2, kt);
    float e1 = expf(ww2 - p2);
    float e2 = expf(kt - p2);
    aa = e1 * aa + e2 * vt;
    bb = e1 * bb + e2;
    pp = p2;
  }
  int idx = ch * 8192 + b * 1024 + c;
  Ca[idx] = aa; Da[idx] = bb; Qa[idx] = pp;
}

__global__ __launch_bounds__(256) void wkv_p2(const float* __restrict__ td,
                                              const float* __restrict__ Ca,
                                              const float* __restrict__ Da,
                                              const float* __restrict__ Qa,
                                              float* __restrict__ Aa,
                                              float* __restrict__ Ba,
                                              float* __restrict__ Pa) {
  int i = blockIdx.x * 256 + threadIdx.x;  // 0..8191 = b*1024+c
  int c = i & (TC_ - 1);
  float wL = -expf(td[c]) * (float)WKV_L;
  float aa = 0.0f, bb = 0.0f, pp = -1e38f;
#pragma unroll 4
  for (int ch = 0; ch < WKV_NCH; ++ch) {
    int idx = ch * 8192 + i;
    Aa[idx] = aa; Ba[idx] = bb; Pa[idx] = pp;
    float ppw = pp + wL;
    float q = Qa[idx];
    float p2 = fmaxf(ppw, q);
    float ea = expf(ppw - p2);
    float eb = expf(q - p2);
    aa = aa * ea + Ca[idx] * eb;
    bb = bb * ea + Da[idx] * eb;
    pp = p2;
  }
}

__global__ __launch_bounds__(256) void wkv_p3(const float* __restrict__ td,
                                              const float* __restrict__ tf,
                                              const short* __restrict__ K,
                                              const short* __restrict__ V,
                                              const short* __restrict__ SR,
                                              short* __restrict__ SRY,
                                              const float* __restrict__ Aa,
                                              const float* __restrict__ Ba,
                                              const float* __restrict__ Pa) {
  int bx = blockIdx.x;
  int ch = bx >> 5;
  int b = (bx >> 2) & 7;
  int c = (bx & 3) * 256 + threadIdx.x;
  float w = -expf(td[c]);
  float u = tf[c];
  int idx = ch * 8192 + b * 1024 + c;
  float aa = Aa[idx], bb = Ba[idx], pp = Pa[idx];
  int64_t base = ((int64_t)b * TT_ + ch * WKV_L) * TC_ + c;
#pragma unroll
  for (int t = 0; t < WKV_L; ++t) {
    int64_t o = base + (int64_t)t * TC_;
    float kt = b2f(K[o]), vt = b2f(V[o]);
    float ww = u + kt;
    float p = fmaxf(pp, ww);
    float E1 = expf(pp - p);
    float E2 = expf(ww - p);
    float y = (E1 * aa + E2 * vt) / (E1 * bb + E2);
    SRY[o] = f2b(y * b2f(SR[o]));
    float ww2 = pp + w;
    float p2 = fmaxf(ww2, kt);
    float e1 = expf(ww2 - p2);
    float e2 = expf(kt - p2);
    aa = e1 * aa + e2 * vt;
    bb = e1 * bb + e2;
    pp = p2;
  }
}

// S[c] = sum_j Wam[c][j] (j<256)
__global__ __launch_bounds__(64) void row_sum256(const float* __restrict__ Wam,
                                                 float* __restrict__ S) {
  int c = blockIdx.x;
  int lane = threadIdx.x;
  float4 v = ((const float4*)(Wam + (int64_t)c * 256))[lane];
  float s = v.x + v.y + v.z + v.w;
  for (int off = 32; off > 0; off >>= 1) s += __shfl_down(s, off);
  if (lane == 0) S[c] = s;
}

// ---------------- bf16 MFMA GEMM ----------------
// C[bz][m][n] = epi( sum_k A[m][k]*B[n][k] ), A: M x K bf16, B: N x K bf16.
// Tile BM x BN (template), BK=32, 256 threads (4 waves 2x2). Single-buffer
// 2-barrier K-loop (R3 structure, measured fastest) + MFMA-lane-order LDS
// (R4 layout, zero bank conflicts: every ds_read_b128 is base + lane*16B).
// EPI: 0 bf16; 1 sigmoid bf16; 2 relu^2 bf16;
//      3 tail-final f32 (e0=brm[m], e1=S[n], e2=bam[n], e3=XC f32, sE);
//      4 C(f32) += lif4(acc); 5 C(f32) += lif4(acc * e3[m][n] bf16);
//      6 z-select: bz==2 ? sigmoid : plain (bf16)
template <int BM, int BN, int EPI>
__global__ __launch_bounds__(256, 2) void gemm_bf16(
    const short* __restrict__ A, const short* __restrict__ B,
    void* __restrict__ Cp, int M, int N, int K,
    int64_t sA, int64_t sB, int64_t sC,
    const float* __restrict__ e0, const float* __restrict__ e1,
    const float* __restrict__ e2, const void* __restrict__ e3, int64_t sE) {
  constexpr int MF = BM / 32;      // m-frags per wave
  constexpr int NF = BN / 32;      // n-frags per wave
  constexpr int ASLOT = BM / 64;   // 16B stage slots per thread for A
  constexpr int BSLOT = BN / 64;
  constexpr int BLDS = BM * 32;    // B tile base (shorts)
  __shared__ short lds[BM * 32 + BN * 32];
  const int tid = threadIdx.x;
  const int bz = blockIdx.z;
  const int brow = blockIdx.y * BM;
  const int bcol = blockIdx.x * BN;
  const short* Ab = A + bz * sA;
  const short* Bb = B + bz * sB;

  // lane-order staging: slot p -> row ((p>>6)<<4)+(p&15), k8 chunk (p>>4)&3
  const int srow = ((tid >> 6) << 4) + (tid & 15);
  const int skc = ((tid >> 4) & 3) * 8;
  const short* gA[ASLOT];
  const short* gB[BSLOT];
#pragma unroll
  for (int s = 0; s < ASLOT; ++s)
    gA[s] = Ab + (int64_t)(brow + s * 64 + srow) * K + skc;
#pragma unroll
  for (int s = 0; s < BSLOT; ++s)
    gB[s] = Bb + (int64_t)(bcol + s * 64 + srow) * K + skc;

  const int lane = tid & 63, wid = tid >> 6;
  const int wr = wid >> 1, wc = wid & 1;

  f32x4 acc[MF][NF] = {};
  for (int k0 = 0; k0 < K; k0 += 32) {
#pragma unroll
    for (int s = 0; s < ASLOT; ++s)
      gload16(gA[s] + k0, lds + s * 2048 + tid * 8);
#pragma unroll
    for (int s = 0; s < BSLOT; ++s)
      gload16(gB[s] + k0, lds + BLDS + s * 2048 + tid * 8);
    __syncthreads();  // drains vmcnt -> tile visible to all waves
    bf16x8 af[MF], bfv[NF];
#pragma unroll
    for (int m = 0; m < MF; ++m)
      af[m] = *(const bf16x8*)(lds + (wr * MF + m) * 512 + lane * 8);
#pragma unroll
    for (int n = 0; n < NF; ++n)
      bfv[n] = *(const bf16x8*)(lds + BLDS + (wc * NF + n) * 512 + lane * 8);
#pragma unroll
    for (int m = 0; m < MF; ++m)
#pragma unroll
      for (int n = 0; n < NF; ++n)
        acc[m][n] = __builtin_amdgcn_mfma_f32_16x16x32_bf16(af[m], bfv[n],
                                                            acc[m][n], 0, 0, 0);
    __syncthreads();  // all reads done before next stage overwrites
  }

  const int r0 = brow + wr * (BM / 2) + (lane >> 4) * 4;
  const int c0 = bcol + wc * (BN / 2) + (lane & 15);
#pragma unroll
  for (int m = 0; m < MF; ++m) {
#pragma unroll
    for (int j = 0; j < 4; ++j) {
      int row = r0 + m * 16 + j;
#pragma unroll
      for (int n = 0; n < NF; ++n) {
        int col = c0 + n * 16;
        float v = acc[m][n][j];
        int64_t idx = (int64_t)row * N + col;
        if (EPI == 0) {
          ((short*)Cp)[bz * sC + idx] = f2b(v);
        } else if (EPI == 1) {
          ((short*)Cp)[bz * sC + idx] = f2b(sigm(v));
        } else if (EPI == 2) {
          v = fmaxf(v, 0.0f);
          ((short*)Cp)[bz * sC + idx] = f2b(v * v);
        } else if (EPI == 3) {
          float r2 = v + e0[row] * e1[col] + e2[col];
          float xo = ((const float*)e3)[bz * sE + idx];
          ((float*)Cp)[bz * sC + idx] = xo * (1.0f + r2);
        } else if (EPI == 4) {
          float* XC = (float*)Cp;
          XC[idx] = XC[idx] + lif4(v);
        } else if (EPI == 5) {
          float* XC = (float*)Cp;
          float srr = b2f(((const short*)e3)[idx]);
          XC[idx] = XC[idx] + lif4(v * srr);
        } else if (EPI == 6) {
          ((short*)Cp)[bz * sC + idx] = f2b(bz == 2 ? sigm(v) : v);
        }
      }
    }
  }
}

// ---------------- launch ----------------
extern "C" void kernel_launch(void* const* d_in, const int* in_sizes, int n_in,
                              void* d_out, int out_size, void* d_ws,
                              size_t ws_size, hipStream_t stream) {
  const float* x   = (const float*)d_in[0];
  const float* rt  = (const float*)d_in[1];
  const float* td  = (const float*)d_in[2];
  const float* tf  = (const float*)d_in[3];
  const float* tmk = (const float*)d_in[4];
  const float* tmv = (const float*)d_in[5];
  const float* tmr = (const float*)d_in[6];
  const float* Wk  = (const float*)d_in[7];
  const float* Wv  = (const float*)d_in[8];
  const float* Wr  = (const float*)d_in[9];
  const float* Wo  = (const float*)d_in[10];
  const float* cmk = (const float*)d_in[11];
  const float* cmr = (const float*)d_in[12];
  const float* Wck = (const float*)d_in[13];
  const float* Wcv = (const float*)d_in[14];
  const float* Wcr = (const float*)d_in[15];
  const float* Wrm = (const float*)d_in[16];
  const float* brm = (const float*)d_in[17];
  const float* Wam = (const float*)d_in[18];
  const float* bam = (const float*)d_in[19];
  float* out = (float*)d_out;

  const size_t MB = 1ull << 20;
  uint8_t* W8 = (uint8_t*)d_ws;
  // Memory map (MB offsets), phase-ordered reuse:
  float* XC   = (float*)(W8);                        // 0-16 residual f32
  short* L    = (short*)(W8 + 16 * MB);              // 16-24 ln out
  short* S1   = (short*)(W8 + 24 * MB);              // 24-32 xk / SRY / SRR / Sb
  short* S2   = (short*)(W8 + 32 * MB);              // 32-40 xv / xk2 / rtok,Mt
  short* S3   = (short*)(W8 + 40 * MB);              // 40-48 xr / xr2 / bWck
  short* bWcv = (short*)(W8 + 48 * MB);              // 48-56
  short* bWk  = (short*)(W8 + 56 * MB);              // 56-62 bWk,bWv,bWr contig
  short* bWo  = (short*)(W8 + 62 * MB);
  short* bWcr = (short*)(W8 + 64 * MB);
  short* bWrm = (short*)(W8 + 66 * MB);              // 0.5 MB
  short* bWam = (short*)(W8 + 66 * MB + 512 * 1024); // 0.5 MB
  short* KK   = (short*)(W8 + 67 * MB);              // 67-75
  short* VV   = (short*)(W8 + 75 * MB);              // 75-83
  short* RR   = (short*)(W8 + 83 * MB);              // 83-91
  float* Ca   = (float*)(W8 + 91 * MB);
  float* Da   = (float*)(W8 + 92 * MB);
  float* Qa   = (float*)(W8 + 93 * MB);
  float* Aa   = (float*)(W8 + 94 * MB);
  float* Ba   = (float*)(W8 + 95 * MB);
  float* Pa   = (float*)(W8 + 96 * MB);
  short* SRY  = S1;
  short* xk2  = S2;
  short* xr2  = S3;
  short* SRR  = S1;
  short* bWck = S3;                                  // after SRR GEMM
  short* H16  = KK;                                  // 67-99 (32 MB)
  short* rtok = S2;                                  // 32-36
  short* Mt   = (short*)(W8 + 36 * MB);              // 36-37
  float* Sb   = (float*)(W8 + 24 * MB);              // 4 KB (SRR dead by then)

  dim3 blk(256);
  const int NV4 = 4096;   // B*T*C/4 / 256
  const int NV8 = 2048;   // B*T*C/8 / 256

  // weight conversions (time-mix + tail)
  cvt_b<<<512, blk, 0, stream>>>(Wk, bWk);
  cvt_b<<<512, blk, 0, stream>>>(Wv, bWk + 1048576);
  cvt_b<<<512, blk, 0, stream>>>(Wr, bWk + 2097152);
  cvt_b<<<512, blk, 0, stream>>>(Wo, bWo);
  cvt_b<<<512, blk, 0, stream>>>(Wcr, bWcr);
  cvt_b<<<128, blk, 0, stream>>>(Wrm, bWrm);
  cvt_b<<<128, blk, 0, stream>>>(Wam, bWam);

  // 1) xc = concat(x, rt); ln1 -> L; mixes -> S1,S2,S3
  build_xc<<<NV4, blk, 0, stream>>>(x, rt, XC);
  ln_rows_b<<<TB_ * TT_, blk, 0, stream>>>(XC, L);
  mix3_b<<<NV8, blk, 0, stream>>>(L, tmk, tmv, tmr, S1, S2, S3);

  // 2) fused z=3 time-mix GEMM: KK = xk*Wk^T, VV = xv*Wv^T, RR = sigm(xr*Wr^T)
  gemm_bf16<128, 64, 6><<<dim3(16, 32, 3), blk, 0, stream>>>(
      S1, bWk, KK, 4096, 1024, 1024, 4194304, 1048576, 4194304,
      nullptr, nullptr, nullptr, nullptr, 0);
  // 3) wkv chunked scan -> SRY (=S1)
  wkv_p1<<<WKV_NCH * TB_ * 4, blk, 0, stream>>>(td, KK, VV, Ca, Da, Qa);
  wkv_p2<<<32, blk, 0, stream>>>(td, Ca, Da, Qa, Aa, Ba, Pa);
  wkv_p3<<<WKV_NCH * TB_ * 4, blk, 0, stream>>>(td, tf, KK, VV, RR, SRY,
                                                Aa, Ba, Pa);
  // 4) att: XC += lif(SRY*Wo^T)
  gemm_bf16<128, 64, 4><<<dim3(16, 32, 1), blk, 0, stream>>>(
      SRY, bWo, XC, 4096, 1024, 1024, 0, 0, 0,
      nullptr, nullptr, nullptr, nullptr, 0);
  // 5) ln2 -> L; mix2 -> xk2(S2), xr2(S3)
  ln_rows_b<<<TB_ * TT_, blk, 0, stream>>>(XC, L);
  mix2_b<<<NV8, blk, 0, stream>>>(L, cmk, cmr, xk2, xr2);
  // 6) SRR = sigm(xr2*Wcr^T) -> S1
  gemm_bf16<128, 64, 1><<<dim3(16, 32, 1), blk, 0, stream>>>(
      xr2, bWcr, SRR, 4096, 1024, 1024, 0, 0, 0,
      nullptr, nullptr, nullptr, nullptr, 0);
  // 7) channel-mix weights into dead regions (xr2 slot, bWcv slot)
  cvt_b<<<2048, blk, 0, stream>>>(Wck, bWck);
  cvt_b<<<2048, blk, 0, stream>>>(Wcv, bWcv);
  // 8) H = relu^2(xk2*Wck^T) -> H16 (4096x4096)
  gemm_bf16<128, 128, 2><<<dim3(32, 32, 1), blk, 0, stream>>>(
      xk2, bWck, H16, 4096, 4096, 1024, 0, 0, 0,
      nullptr, nullptr, nullptr, nullptr, 0);
  // 9) XC += lif(SRR * (H*Wcv^T))
  gemm_bf16<128, 64, 5><<<dim3(16, 32, 1), blk, 0, stream>>>(
      H16, bWcv, XC, 4096, 1024, 4096, 0, 0, 0,
      nullptr, nullptr, nullptr, SRR, 0);
  // 10) tail
  cvt_rtok<<<1024, blk, 0, stream>>>(XC, rtok);
  gemm_bf16<64, 64, 0><<<dim3(4, 4, 8), blk, 0, stream>>>(
      bWrm, rtok, Mt, 256, 256, 1024, 0, (int64_t)256 * 1024,
      (int64_t)256 * 256, nullptr, nullptr, nullptr, nullptr, 0);
  row_sum256<<<1024, dim3(64), 0, stream>>>(Wam, Sb);
  gemm_bf16<64, 64, 3><<<dim3(16, 4, 8), blk, 0, stream>>>(
      Mt, bWam, out, 256, 1024, 256, (int64_t)256 * 256, 0,
      (int64_t)256 * 1024, brm, Sb, bam, XC, (int64_t)512 * 1024);
}

// Round 6
// 368.240 us; speedup vs baseline: 1.1994x; 1.1994x over previous
//
#include <hip/hip_runtime.h>
#include <hip/hip_bf16.h>
#include <math.h>
#include <stdint.h>

// B=8, P1=256 -> T=512 concat rows, C=1024, H=4096
#define TB_ 8
#define TT_ 512
#define TC_ 1024
// wkv chunked scan: 32 chunks of 16 steps
#define WKV_NCH 32
#define WKV_L 16

typedef __attribute__((ext_vector_type(8))) short bf16x8;
typedef __attribute__((ext_vector_type(4))) short s16x4;
typedef __attribute__((ext_vector_type(4))) float f32x4;

__device__ __forceinline__ float b2f(short u) {
  union { unsigned int i; float f; } x;
  x.i = ((unsigned int)(unsigned short)u) << 16;
  return x.f;
}
__device__ __forceinline__ short f2b(float f) {
  __hip_bfloat16 h = __float2bfloat16(f);  // RNE
  return __builtin_bit_cast(short, h);
}
__device__ __forceinline__ float sigm(float x) { return 1.0f / (1.0f + expf(-x)); }

// LIF over 4 identical inputs (closed form of the reference scan), TAU=2, VTH=1
__device__ __forceinline__ float lif4(float a) {
  float v = 0.0f, acc = 0.0f;
#pragma unroll
  for (int i = 0; i < 4; ++i) {
    v += (a - v) * 0.5f;
    float s = (v >= 1.0f) ? 1.0f : 0.0f;
    acc += s;
    v *= (1.0f - s);
  }
  return acc * 0.25f;
}

__device__ __forceinline__ void gload16(const void* g, void* l) {
  __builtin_amdgcn_global_load_lds(
      (__attribute__((address_space(1))) void*)(g),
      (__attribute__((address_space(3))) void*)(l), 16, 0, 0);
}

// ---------------- elementwise kernels ----------------

__global__ __launch_bounds__(256) void build_xc(const float* __restrict__ x,
                                                const float* __restrict__ rt,
                                                float* __restrict__ xc) {
  int i = blockIdx.x * 256 + threadIdx.x;  // float4 index over B*T*C/4
  int c4 = i & 255;
  int t = (i >> 8) & 511;
  int b = i >> 17;
  float4 v;
  if (t < 256)
    v = ((const float4*)x)[(b * 256 + t) * 256 + c4];
  else
    v = ((const float4*)rt)[(t - 256) * 256 + c4];
  ((float4*)xc)[i] = v;
}

// LayerNorm each row (C=1024 f32) -> bf16. One 256-thread block per row.
__global__ __launch_bounds__(256) void ln_rows_b(const float* __restrict__ src,
                                                 short* __restrict__ dst) {
  __shared__ float red[256];
  int64_t row = blockIdx.x;
  float4 v = ((const float4*)(src + row * TC_))[threadIdx.x];
  red[threadIdx.x] = v.x + v.y + v.z + v.w;
  __syncthreads();
  for (int off = 128; off > 0; off >>= 1) {
    if (threadIdx.x < off) red[threadIdx.x] += red[threadIdx.x + off];
    __syncthreads();
  }
  float mean = red[0] * (1.0f / 1024.0f);
  __syncthreads();
  float dx = v.x - mean, dy = v.y - mean, dz = v.z - mean, dw = v.w - mean;
  red[threadIdx.x] = dx * dx + dy * dy + dz * dz + dw * dw;
  __syncthreads();
  for (int off = 128; off > 0; off >>= 1) {
    if (threadIdx.x < off) red[threadIdx.x] += red[threadIdx.x + off];
    __syncthreads();
  }
  float rs = 1.0f / sqrtf(red[0] * (1.0f / 1024.0f) + 1e-6f);
  s16x4 o;
  o.x = f2b(dx * rs); o.y = f2b(dy * rs); o.z = f2b(dz * rs); o.w = f2b(dw * rs);
  *(s16x4*)(dst + row * TC_ + threadIdx.x * 4) = o;
}

// time-mix blends from bf16 LN. 8 elems/thread; i over B*T*C/8.
__global__ __launch_bounds__(256) void mix3_b(const short* __restrict__ ln,
                                              const float* __restrict__ tk,
                                              const float* __restrict__ tv,
                                              const float* __restrict__ tr,
                                              short* __restrict__ xk,
                                              short* __restrict__ xv,
                                              short* __restrict__ xr) {
  int i = blockIdx.x * 256 + threadIdx.x;  // short8 index
  int c8 = i & 127;
  int t = (i >> 7) & 511;
  bf16x8 h = *(const bf16x8*)(ln + (int64_t)i * 8);
  bf16x8 s = {};
  if (t > 0) s = *(const bf16x8*)(ln + (int64_t)(i - 128) * 8);
  bf16x8 ok, ov, orr;
#pragma unroll
  for (int e = 0; e < 8; ++e) {
    float hf = b2f(h[e]), sf = b2f(s[e]);
    int c = c8 * 8 + e;
    float mk = tk[c], mv = tv[c], mr = tr[c];
    ok[e] = f2b(hf * mk + sf * (1.0f - mk));
    ov[e] = f2b(hf * mv + sf * (1.0f - mv));
    orr[e] = f2b(hf * mr + sf * (1.0f - mr));
  }
  *(bf16x8*)(xk + (int64_t)i * 8) = ok;
  *(bf16x8*)(xv + (int64_t)i * 8) = ov;
  *(bf16x8*)(xr + (int64_t)i * 8) = orr;
}

__global__ __launch_bounds__(256) void mix2_b(const short* __restrict__ ln,
                                              const float* __restrict__ tk,
                                              const float* __restrict__ tr,
                                              short* __restrict__ xk,
                                              short* __restrict__ xr) {
  int i = blockIdx.x * 256 + threadIdx.x;
  int c8 = i & 127;
  int t = (i >> 7) & 511;
  bf16x8 h = *(const bf16x8*)(ln + (int64_t)i * 8);
  bf16x8 s = {};
  if (t > 0) s = *(const bf16x8*)(ln + (int64_t)(i - 128) * 8);
  bf16x8 ok, orr;
#pragma unroll
  for (int e = 0; e < 8; ++e) {
    float hf = b2f(h[e]), sf = b2f(s[e]);
    int c = c8 * 8 + e;
    float mk = tk[c], mr = tr[c];
    ok[e] = f2b(hf * mk + sf * (1.0f - mk));
    orr[e] = f2b(hf * mr + sf * (1.0f - mr));
  }
  *(bf16x8*)(xk + (int64_t)i * 8) = ok;
  *(bf16x8*)(xr + (int64_t)i * 8) = orr;
}

// f32 -> bf16, 8 elems/thread
__global__ __launch_bounds__(256) void cvt_b(const float* __restrict__ src,
                                             short* __restrict__ dst) {
  int64_t i = (int64_t)(blockIdx.x * 256 + threadIdx.x) * 8;
  float4 a = *(const float4*)(src + i);
  float4 b = *(const float4*)(src + i + 4);
  bf16x8 o;
  o[0] = f2b(a.x); o[1] = f2b(a.y); o[2] = f2b(a.z); o[3] = f2b(a.w);
  o[4] = f2b(b.x); o[5] = f2b(b.y); o[6] = f2b(b.z); o[7] = f2b(b.w);
  *(bf16x8*)(dst + i) = o;
}

// rtok rows (per b: rows 256..511 of XC) f32 -> bf16 contiguous (B,256,C)
__global__ __launch_bounds__(256) void cvt_rtok(const float* __restrict__ xc,
                                                short* __restrict__ dst) {
  int i = blockIdx.x * 256 + threadIdx.x;  // short8 idx
  int b = i >> 15;
  int rem = i & 32767;
  const float* s = xc + (int64_t)b * 524288 + 262144 + (int64_t)rem * 8;
  float4 a = *(const float4*)s;
  float4 c = *(const float4*)(s + 4);
  bf16x8 o;
  o[0] = f2b(a.x); o[1] = f2b(a.y); o[2] = f2b(a.z); o[3] = f2b(a.w);
  o[4] = f2b(c.x); o[5] = f2b(c.y); o[6] = f2b(c.z); o[7] = f2b(c.w);
  *(bf16x8*)(dst + (int64_t)i * 8) = o;
}

// ---------------- wkv chunked parallel scan ----------------
__global__ __launch_bounds__(256) void wkv_p1(const float* __restrict__ td,
                                              const short* __restrict__ K,
                                              const short* __restrict__ V,
                                              float* __restrict__ Ca,
                                              float* __restrict__ Da,
                                              float* __restrict__ Qa) {
  int bx = blockIdx.x;  // [ch:5][b:3][cg:2]
  int ch = bx >> 5;
  int b = (bx >> 2) & 7;
  int c = (bx & 3) * 256 + threadIdx.x;
  float w = -expf(td[c]);
  float aa = 0.0f, bb = 0.0f, pp = -1e38f;
  int64_t base = ((int64_t)b * TT_ + ch * WKV_L) * TC_ + c;
#pragma unroll
  for (int t = 0; t < WKV_L; ++t) {
    int64_t o = base + (int64_t)t * TC_;
    float kt = b2f(K[o]), vt = b2f(V[o]);
    float ww2 = pp + w;
    float p2 = fmaxf(ww2, kt);
    float e1 = expf(ww2 - p2);
    float e2 = expf(kt - p2);
    aa = e1 * aa + e2 * vt;
    bb = e1 * bb + e2;
    pp = p2;
  }
  int idx = ch * 8192 + b * 1024 + c;
  Ca[idx] = aa; Da[idx] = bb; Qa[idx] = pp;
}

__global__ __launch_bounds__(256) void wkv_p2(const float* __restrict__ td,
                                              const float* __restrict__ Ca,
                                              const float* __restrict__ Da,
                                              const float* __restrict__ Qa,
                                              float* __restrict__ Aa,
                                              float* __restrict__ Ba,
                                              float* __restrict__ Pa) {
  int i = blockIdx.x * 256 + threadIdx.x;  // 0..8191 = b*1024+c
  int c = i & (TC_ - 1);
  float wL = -expf(td[c]) * (float)WKV_L;
  float aa = 0.0f, bb = 0.0f, pp = -1e38f;
#pragma unroll 4
  for (int ch = 0; ch < WKV_NCH; ++ch) {
    int idx = ch * 8192 + i;
    Aa[idx] = aa; Ba[idx] = bb; Pa[idx] = pp;
    float ppw = pp + wL;
    float q = Qa[idx];
    float p2 = fmaxf(ppw, q);
    float ea = expf(ppw - p2);
    float eb = expf(q - p2);
    aa = aa * ea + Ca[idx] * eb;
    bb = bb * ea + Da[idx] * eb;
    pp = p2;
  }
}

__global__ __launch_bounds__(256) void wkv_p3(const float* __restrict__ td,
                                              const float* __restrict__ tf,
                                              const short* __restrict__ K,
                                              const short* __restrict__ V,
                                              const short* __restrict__ SR,
                                              short* __restrict__ SRY,
                                              const float* __restrict__ Aa,
                                              const float* __restrict__ Ba,
                                              const float* __restrict__ Pa) {
  int bx = blockIdx.x;
  int ch = bx >> 5;
  int b = (bx >> 2) & 7;
  int c = (bx & 3) * 256 + threadIdx.x;
  float w = -expf(td[c]);
  float u = tf[c];
  int idx = ch * 8192 + b * 1024 + c;
  float aa = Aa[idx], bb = Ba[idx], pp = Pa[idx];
  int64_t base = ((int64_t)b * TT_ + ch * WKV_L) * TC_ + c;
#pragma unroll
  for (int t = 0; t < WKV_L; ++t) {
    int64_t o = base + (int64_t)t * TC_;
    float kt = b2f(K[o]), vt = b2f(V[o]);
    float ww = u + kt;
    float p = fmaxf(pp, ww);
    float E1 = expf(pp - p);
    float E2 = expf(ww - p);
    float y = (E1 * aa + E2 * vt) / (E1 * bb + E2);
    SRY[o] = f2b(y * b2f(SR[o]));
    float ww2 = pp + w;
    float p2 = fmaxf(ww2, kt);
    float e1 = expf(ww2 - p2);
    float e2 = expf(kt - p2);
    aa = e1 * aa + e2 * vt;
    bb = e1 * bb + e2;
    pp = p2;
  }
}

// S[c] = sum_j Wam[c][j] (j<256)
__global__ __launch_bounds__(64) void row_sum256(const float* __restrict__ Wam,
                                                 float* __restrict__ S) {
  int c = blockIdx.x;
  int lane = threadIdx.x;
  float4 v = ((const float4*)(Wam + (int64_t)c * 256))[lane];
  float s = v.x + v.y + v.z + v.w;
  for (int off = 32; off > 0; off >>= 1) s += __shfl_down(s, off);
  if (lane == 0) S[c] = s;
}

// ---------------- bf16 MFMA GEMM ----------------
// C[bz][m][n] = epi( sum_k A[m][k]*B[n][k] ), A: M x K bf16, B: N x K bf16.
// BM x BN tile, BK=32, 256 threads (4 waves 2x2). Double-buffered LDS in
// MFMA lane order (0 bank conflicts) + COUNTED-vmcnt pipeline: prefetch of
// tile t+1 stays in flight across the raw s_barrier (never vmcnt(0) in the
// main loop) -- the fix for the __syncthreads full-drain stall (R4).
// XCD chunked swizzle (bijective, requires nwg%8==0) for L2 A-panel reuse.
// EPI: 0 bf16; 1 sigmoid bf16; 2 relu^2 bf16;
//      3 tail-final f32 (e0=brm[m], e1=S[n], e2=bam[n], e3=XC f32, sE);
//      4 C(f32) += lif4(acc); 5 C(f32) += lif4(acc * e3[m][n] bf16);
//      6 z-select: bz==2 ? sigmoid : plain (bf16)
template <int BM, int BN, int EPI>
__global__ __launch_bounds__(256, 2) void gemm_bf16(
    const short* __restrict__ A, const short* __restrict__ B,
    void* __restrict__ Cp, int M, int N, int K,
    int64_t sA, int64_t sB, int64_t sC,
    const float* __restrict__ e0, const float* __restrict__ e1,
    const float* __restrict__ e2, const void* __restrict__ e3, int64_t sE) {
  constexpr int MF = BM / 32;      // m-frags per wave
  constexpr int NF = BN / 32;      // n-frags per wave
  constexpr int ASLOT = BM / 64;   // 16B stage slots per thread for A
  constexpr int BSLOT = BN / 64;
  constexpr int SBUF = (BM + BN) * 32;  // shorts per LDS buffer
  __shared__ short lds[2 * SBUF];
  const int tid = threadIdx.x;

  // bijective XCD chunked swizzle (m204): consecutive new-ids share an XCD
  const unsigned gx = gridDim.x, gy = gridDim.y;
  const unsigned nwg = gx * gy * gridDim.z;
  const unsigned lin = blockIdx.x + gx * (blockIdx.y + gy * blockIdx.z);
  const unsigned cs = nwg >> 3;
  const unsigned nl = (lin & 7) * cs + (lin >> 3);
  const unsigned bxs = nl % gx;
  const unsigned tmp = nl / gx;
  const unsigned bys = tmp % gy;
  const unsigned bz = tmp / gy;

  const int brow = bys * BM;
  const int bcol = bxs * BN;
  const short* Ab = A + bz * sA;
  const short* Bb = B + bz * sB;

  // lane-order staging: slot p -> row ((p>>6)<<4)+(p&15), k8 chunk (p>>4)&3
  const int srow = ((tid >> 6) << 4) + (tid & 15);
  const int skc = ((tid >> 4) & 3) * 8;
  const short* gA[ASLOT];
  const short* gB[BSLOT];
#pragma unroll
  for (int s = 0; s < ASLOT; ++s)
    gA[s] = Ab + (int64_t)(brow + s * 64 + srow) * K + skc;
#pragma unroll
  for (int s = 0; s < BSLOT; ++s)
    gB[s] = Bb + (int64_t)(bcol + s * 64 + srow) * K + skc;

  const int lane = tid & 63, wid = tid >> 6;
  const int wr = wid >> 1, wc = wid & 1;

  f32x4 acc[MF][NF] = {};

  auto stage = [&](int buf, int k0) {
    short* d = lds + buf * SBUF;
#pragma unroll
    for (int s = 0; s < ASLOT; ++s)
      gload16(gA[s] + k0, d + s * 2048 + tid * 8);
#pragma unroll
    for (int s = 0; s < BSLOT; ++s)
      gload16(gB[s] + k0, d + BM * 32 + s * 2048 + tid * 8);
  };
  auto compute = [&](int buf) {
    const short* base = lds + buf * SBUF;
    bf16x8 af[MF], bfv[NF];
#pragma unroll
    for (int m = 0; m < MF; ++m)
      af[m] = *(const bf16x8*)(base + (wr * MF + m) * 512 + lane * 8);
#pragma unroll
    for (int n = 0; n < NF; ++n)
      bfv[n] = *(const bf16x8*)(base + BM * 32 + (wc * NF + n) * 512 + lane * 8);
#pragma unroll
    for (int m = 0; m < MF; ++m)
#pragma unroll
      for (int n = 0; n < NF; ++n)
        acc[m][n] = __builtin_amdgcn_mfma_f32_16x16x32_bf16(af[m], bfv[n],
                                                            acc[m][n], 0, 0, 0);
  };

  const int nst = K / 32;
  stage(0, 0);
  for (int st = 0; st < nst - 1; ++st) {
    stage((st + 1) & 1, (st + 1) * 32);
    // wait own tile-st loads (the NS newer tile-(st+1) loads stay in flight),
    // then barrier -> all waves' tile-st loads done -> tile resident.
    if constexpr (ASLOT + BSLOT == 4)
      asm volatile("s_waitcnt vmcnt(4)" ::: "memory");
    else if constexpr (ASLOT + BSLOT == 3)
      asm volatile("s_waitcnt vmcnt(3)" ::: "memory");
    else
      asm volatile("s_waitcnt vmcnt(2)" ::: "memory");
    asm volatile("s_barrier" ::: "memory");
    compute(st & 1);
    asm volatile("s_barrier" ::: "memory");  // reads done before overwrite
  }
  asm volatile("s_waitcnt vmcnt(0)" ::: "memory");
  asm volatile("s_barrier" ::: "memory");
  compute((nst - 1) & 1);

  const int r0 = brow + wr * (BM / 2) + (lane >> 4) * 4;
  const int c0 = bcol + wc * (BN / 2) + (lane & 15);
#pragma unroll
  for (int m = 0; m < MF; ++m) {
#pragma unroll
    for (int j = 0; j < 4; ++j) {
      int row = r0 + m * 16 + j;
#pragma unroll
      for (int n = 0; n < NF; ++n) {
        int col = c0 + n * 16;
        float v = acc[m][n][j];
        int64_t idx = (int64_t)row * N + col;
        if (EPI == 0) {
          ((short*)Cp)[bz * sC + idx] = f2b(v);
        } else if (EPI == 1) {
          ((short*)Cp)[bz * sC + idx] = f2b(sigm(v));
        } else if (EPI == 2) {
          v = fmaxf(v, 0.0f);
          ((short*)Cp)[bz * sC + idx] = f2b(v * v);
        } else if (EPI == 3) {
          float r2 = v + e0[row] * e1[col] + e2[col];
          float xo = ((const float*)e3)[bz * sE + idx];
          ((float*)Cp)[bz * sC + idx] = xo * (1.0f + r2);
        } else if (EPI == 4) {
          float* XC = (float*)Cp;
          XC[idx] = XC[idx] + lif4(v);
        } else if (EPI == 5) {
          float* XC = (float*)Cp;
          float srr = b2f(((const short*)e3)[idx]);
          XC[idx] = XC[idx] + lif4(v * srr);
        } else if (EPI == 6) {
          ((short*)Cp)[bz * sC + idx] = f2b(bz == 2 ? sigm(v) : v);
        }
      }
    }
  }
}

// ---------------- launch ----------------
extern "C" void kernel_launch(void* const* d_in, const int* in_sizes, int n_in,
                              void* d_out, int out_size, void* d_ws,
                              size_t ws_size, hipStream_t stream) {
  const float* x   = (const float*)d_in[0];
  const float* rt  = (const float*)d_in[1];
  const float* td  = (const float*)d_in[2];
  const float* tf  = (const float*)d_in[3];
  const float* tmk = (const float*)d_in[4];
  const float* tmv = (const float*)d_in[5];
  const float* tmr = (const float*)d_in[6];
  const float* Wk  = (const float*)d_in[7];
  const float* Wv  = (const float*)d_in[8];
  const float* Wr  = (const float*)d_in[9];
  const float* Wo  = (const float*)d_in[10];
  const float* cmk = (const float*)d_in[11];
  const float* cmr = (const float*)d_in[12];
  const float* Wck = (const float*)d_in[13];
  const float* Wcv = (const float*)d_in[14];
  const float* Wcr = (const float*)d_in[15];
  const float* Wrm = (const float*)d_in[16];
  const float* brm = (const float*)d_in[17];
  const float* Wam = (const float*)d_in[18];
  const float* bam = (const float*)d_in[19];
  float* out = (float*)d_out;

  const size_t MB = 1ull << 20;
  uint8_t* W8 = (uint8_t*)d_ws;
  // Memory map (MB offsets), phase-ordered reuse:
  float* XC   = (float*)(W8);                        // 0-16 residual f32
  short* L    = (short*)(W8 + 16 * MB);              // 16-24 ln out
  short* S1   = (short*)(W8 + 24 * MB);              // 24-32 xk / SRY / SRR / Sb
  short* S2   = (short*)(W8 + 32 * MB);              // 32-40 xv / xk2 / rtok,Mt
  short* S3   = (short*)(W8 + 40 * MB);              // 40-48 xr / xr2 / bWck
  short* bWcv = (short*)(W8 + 48 * MB);              // 48-56
  short* bWk  = (short*)(W8 + 56 * MB);              // 56-62 bWk,bWv,bWr contig
  short* bWo  = (short*)(W8 + 62 * MB);
  short* bWcr = (short*)(W8 + 64 * MB);
  short* bWrm = (short*)(W8 + 66 * MB);              // 0.5 MB
  short* bWam = (short*)(W8 + 66 * MB + 512 * 1024); // 0.5 MB
  short* KK   = (short*)(W8 + 67 * MB);              // 67-75
  short* VV   = (short*)(W8 + 75 * MB);              // 75-83
  short* RR   = (short*)(W8 + 83 * MB);              // 83-91
  float* Ca   = (float*)(W8 + 91 * MB);
  float* Da   = (float*)(W8 + 92 * MB);
  float* Qa   = (float*)(W8 + 93 * MB);
  float* Aa   = (float*)(W8 + 94 * MB);
  float* Ba   = (float*)(W8 + 95 * MB);
  float* Pa   = (float*)(W8 + 96 * MB);
  short* SRY  = S1;
  short* xk2  = S2;
  short* xr2  = S3;
  short* SRR  = S1;
  short* bWck = S3;                                  // after SRR GEMM
  short* H16  = KK;                                  // 67-99 (32 MB)
  short* rtok = S2;                                  // 32-36
  short* Mt   = (short*)(W8 + 36 * MB);              // 36-37
  float* Sb   = (float*)(W8 + 24 * MB);              // 4 KB (SRR dead by then)

  dim3 blk(256);
  const int NV4 = 4096;   // B*T*C/4 / 256
  const int NV8 = 2048;   // B*T*C/8 / 256

  // weight conversions (time-mix + tail)
  cvt_b<<<512, blk, 0, stream>>>(Wk, bWk);
  cvt_b<<<512, blk, 0, stream>>>(Wv, bWk + 1048576);
  cvt_b<<<512, blk, 0, stream>>>(Wr, bWk + 2097152);
  cvt_b<<<512, blk, 0, stream>>>(Wo, bWo);
  cvt_b<<<512, blk, 0, stream>>>(Wcr, bWcr);
  cvt_b<<<128, blk, 0, stream>>>(Wrm, bWrm);
  cvt_b<<<128, blk, 0, stream>>>(Wam, bWam);

  // 1) xc = concat(x, rt); ln1 -> L; mixes -> S1,S2,S3
  build_xc<<<NV4, blk, 0, stream>>>(x, rt, XC);
  ln_rows_b<<<TB_ * TT_, blk, 0, stream>>>(XC, L);
  mix3_b<<<NV8, blk, 0, stream>>>(L, tmk, tmv, tmr, S1, S2, S3);

  // 2) fused z=3 time-mix GEMM: KK = xk*Wk^T, VV = xv*Wv^T, RR = sigm(xr*Wr^T)
  gemm_bf16<128, 128, 6><<<dim3(8, 32, 3), blk, 0, stream>>>(
      S1, bWk, KK, 4096, 1024, 1024, 4194304, 1048576, 4194304,
      nullptr, nullptr, nullptr, nullptr, 0);
  // 3) wkv chunked scan -> SRY (=S1)
  wkv_p1<<<WKV_NCH * TB_ * 4, blk, 0, stream>>>(td, KK, VV, Ca, Da, Qa);
  wkv_p2<<<32, blk, 0, stream>>>(td, Ca, Da, Qa, Aa, Ba, Pa);
  wkv_p3<<<WKV_NCH * TB_ * 4, blk, 0, stream>>>(td, tf, KK, VV, RR, SRY,
                                                Aa, Ba, Pa);
  // 4) att: XC += lif(SRY*Wo^T)
  gemm_bf16<128, 128, 4><<<dim3(8, 32, 1), blk, 0, stream>>>(
      SRY, bWo, XC, 4096, 1024, 1024, 0, 0, 0,
      nullptr, nullptr, nullptr, nullptr, 0);
  // 5) ln2 -> L; mix2 -> xk2(S2), xr2(S3)
  ln_rows_b<<<TB_ * TT_, blk, 0, stream>>>(XC, L);
  mix2_b<<<NV8, blk, 0, stream>>>(L, cmk, cmr, xk2, xr2);
  // 6) SRR = sigm(xr2*Wcr^T) -> S1
  gemm_bf16<128, 128, 1><<<dim3(8, 32, 1), blk, 0, stream>>>(
      xr2, bWcr, SRR, 4096, 1024, 1024, 0, 0, 0,
      nullptr, nullptr, nullptr, nullptr, 0);
  // 7) channel-mix weights into dead regions (xr2 slot, bWcv slot)
  cvt_b<<<2048, blk, 0, stream>>>(Wck, bWck);
  cvt_b<<<2048, blk, 0, stream>>>(Wcv, bWcv);
  // 8) H = relu^2(xk2*Wck^T) -> H16 (4096x4096)
  gemm_bf16<128, 128, 2><<<dim3(32, 32, 1), blk, 0, stream>>>(
      xk2, bWck, H16, 4096, 4096, 1024, 0, 0, 0,
      nullptr, nullptr, nullptr, nullptr, 0);
  // 9) XC += lif(SRR * (H*Wcv^T))
  gemm_bf16<128, 128, 5><<<dim3(8, 32, 1), blk, 0, stream>>>(
      H16, bWcv, XC, 4096, 1024, 4096, 0, 0, 0,
      nullptr, nullptr, nullptr, SRR, 0);
  // 10) tail
  cvt_rtok<<<1024, blk, 0, stream>>>(XC, rtok);
  gemm_bf16<64, 64, 0><<<dim3(4, 4, 8), blk, 0, stream>>>(
      bWrm, rtok, Mt, 256, 256, 1024, 0, (int64_t)256 * 1024,
      (int64_t)256 * 256, nullptr, nullptr, nullptr, nullptr, 0);
  row_sum256<<<1024, dim3(64), 0, stream>>>(Wam, Sb);
  gemm_bf16<64, 64, 3><<<dim3(16, 4, 8), blk, 0, stream>>>(
      Mt, bWam, out, 256, 1024, 256, (int64_t)256 * 256, 0,
      (int64_t)256 * 1024, brm, Sb, bam, XC, (int64_t)512 * 1024);
}

// Round 7
// 355.840 us; speedup vs baseline: 1.2412x; 1.0348x over previous
//
#include <hip/hip_runtime.h>
#include <hip/hip_bf16.h>
#include <math.h>
#include <stdint.h>

// B=8, P1=256 -> T=512 concat rows, C=1024, H=4096
#define TB_ 8
#define TT_ 512
#define TC_ 1024
// wkv chunked scan: 32 chunks of 16 steps
#define WKV_NCH 32
#define WKV_L 16

typedef __attribute__((ext_vector_type(8))) short bf16x8;
typedef __attribute__((ext_vector_type(4))) short s16x4;
typedef __attribute__((ext_vector_type(4))) float f32x4;

__device__ __forceinline__ float b2f(short u) {
  union { unsigned int i; float f; } x;
  x.i = ((unsigned int)(unsigned short)u) << 16;
  return x.f;
}
__device__ __forceinline__ short f2b(float f) {
  __hip_bfloat16 h = __float2bfloat16(f);  // RNE
  return __builtin_bit_cast(short, h);
}
__device__ __forceinline__ float sigm(float x) { return 1.0f / (1.0f + expf(-x)); }

// LIF over 4 identical inputs (closed form of the reference scan), TAU=2, VTH=1
__device__ __forceinline__ float lif4(float a) {
  float v = 0.0f, acc = 0.0f;
#pragma unroll
  for (int i = 0; i < 4; ++i) {
    v += (a - v) * 0.5f;
    float s = (v >= 1.0f) ? 1.0f : 0.0f;
    acc += s;
    v *= (1.0f - s);
  }
  return acc * 0.25f;
}

__device__ __forceinline__ void gload16(const void* g, void* l) {
  __builtin_amdgcn_global_load_lds(
      (__attribute__((address_space(1))) void*)(g),
      (__attribute__((address_space(3))) void*)(l), 16, 0, 0);
}

// counted vmcnt wait (compile-time immediate)
template <int N>
__device__ __forceinline__ void waitv() {
  if constexpr (N == 0)  asm volatile("s_waitcnt vmcnt(0)" ::: "memory");
  else if constexpr (N == 2)  asm volatile("s_waitcnt vmcnt(2)" ::: "memory");
  else if constexpr (N == 3)  asm volatile("s_waitcnt vmcnt(3)" ::: "memory");
  else if constexpr (N == 4)  asm volatile("s_waitcnt vmcnt(4)" ::: "memory");
  else if constexpr (N == 6)  asm volatile("s_waitcnt vmcnt(6)" ::: "memory");
  else if constexpr (N == 8)  asm volatile("s_waitcnt vmcnt(8)" ::: "memory");
  else if constexpr (N == 9)  asm volatile("s_waitcnt vmcnt(9)" ::: "memory");
  else if constexpr (N == 12) asm volatile("s_waitcnt vmcnt(12)" ::: "memory");
  else static_assert(N == 0, "unsupported vmcnt");
}
__device__ __forceinline__ void barrier_() {
  asm volatile("s_barrier" ::: "memory");
}

// ---------------- elementwise kernels ----------------

__global__ __launch_bounds__(256) void build_xc(const float* __restrict__ x,
                                                const float* __restrict__ rt,
                                                float* __restrict__ xc) {
  int i = blockIdx.x * 256 + threadIdx.x;  // float4 index over B*T*C/4
  int c4 = i & 255;
  int t = (i >> 8) & 511;
  int b = i >> 17;
  float4 v;
  if (t < 256)
    v = ((const float4*)x)[(b * 256 + t) * 256 + c4];
  else
    v = ((const float4*)rt)[(t - 256) * 256 + c4];
  ((float4*)xc)[i] = v;
}

// LayerNorm each row (C=1024 f32) -> bf16. One 256-thread block per row.
__global__ __launch_bounds__(256) void ln_rows_b(const float* __restrict__ src,
                                                 short* __restrict__ dst) {
  __shared__ float red[256];
  int64_t row = blockIdx.x;
  float4 v = ((const float4*)(src + row * TC_))[threadIdx.x];
  red[threadIdx.x] = v.x + v.y + v.z + v.w;
  __syncthreads();
  for (int off = 128; off > 0; off >>= 1) {
    if (threadIdx.x < off) red[threadIdx.x] += red[threadIdx.x + off];
    __syncthreads();
  }
  float mean = red[0] * (1.0f / 1024.0f);
  __syncthreads();
  float dx = v.x - mean, dy = v.y - mean, dz = v.z - mean, dw = v.w - mean;
  red[threadIdx.x] = dx * dx + dy * dy + dz * dz + dw * dw;
  __syncthreads();
  for (int off = 128; off > 0; off >>= 1) {
    if (threadIdx.x < off) red[threadIdx.x] += red[threadIdx.x + off];
    __syncthreads();
  }
  float rs = 1.0f / sqrtf(red[0] * (1.0f / 1024.0f) + 1e-6f);
  s16x4 o;
  o.x = f2b(dx * rs); o.y = f2b(dy * rs); o.z = f2b(dz * rs); o.w = f2b(dw * rs);
  *(s16x4*)(dst + row * TC_ + threadIdx.x * 4) = o;
}

// time-mix blends from bf16 LN. 8 elems/thread; i over B*T*C/8.
__global__ __launch_bounds__(256) void mix3_b(const short* __restrict__ ln,
                                              const float* __restrict__ tk,
                                              const float* __restrict__ tv,
                                              const float* __restrict__ tr,
                                              short* __restrict__ xk,
                                              short* __restrict__ xv,
                                              short* __restrict__ xr) {
  int i = blockIdx.x * 256 + threadIdx.x;  // short8 index
  int c8 = i & 127;
  int t = (i >> 7) & 511;
  bf16x8 h = *(const bf16x8*)(ln + (int64_t)i * 8);
  bf16x8 s = {};
  if (t > 0) s = *(const bf16x8*)(ln + (int64_t)(i - 128) * 8);
  bf16x8 ok, ov, orr;
#pragma unroll
  for (int e = 0; e < 8; ++e) {
    float hf = b2f(h[e]), sf = b2f(s[e]);
    int c = c8 * 8 + e;
    float mk = tk[c], mv = tv[c], mr = tr[c];
    ok[e] = f2b(hf * mk + sf * (1.0f - mk));
    ov[e] = f2b(hf * mv + sf * (1.0f - mv));
    orr[e] = f2b(hf * mr + sf * (1.0f - mr));
  }
  *(bf16x8*)(xk + (int64_t)i * 8) = ok;
  *(bf16x8*)(xv + (int64_t)i * 8) = ov;
  *(bf16x8*)(xr + (int64_t)i * 8) = orr;
}

__global__ __launch_bounds__(256) void mix2_b(const short* __restrict__ ln,
                                              const float* __restrict__ tk,
                                              const float* __restrict__ tr,
                                              short* __restrict__ xk,
                                              short* __restrict__ xr) {
  int i = blockIdx.x * 256 + threadIdx.x;
  int c8 = i & 127;
  int t = (i >> 7) & 511;
  bf16x8 h = *(const bf16x8*)(ln + (int64_t)i * 8);
  bf16x8 s = {};
  if (t > 0) s = *(const bf16x8*)(ln + (int64_t)(i - 128) * 8);
  bf16x8 ok, orr;
#pragma unroll
  for (int e = 0; e < 8; ++e) {
    float hf = b2f(h[e]), sf = b2f(s[e]);
    int c = c8 * 8 + e;
    float mk = tk[c], mr = tr[c];
    ok[e] = f2b(hf * mk + sf * (1.0f - mk));
    orr[e] = f2b(hf * mr + sf * (1.0f - mr));
  }
  *(bf16x8*)(xk + (int64_t)i * 8) = ok;
  *(bf16x8*)(xr + (int64_t)i * 8) = orr;
}

// f32 -> bf16, 8 elems/thread
__global__ __launch_bounds__(256) void cvt_b(const float* __restrict__ src,
                                             short* __restrict__ dst) {
  int64_t i = (int64_t)(blockIdx.x * 256 + threadIdx.x) * 8;
  float4 a = *(const float4*)(src + i);
  float4 b = *(const float4*)(src + i + 4);
  bf16x8 o;
  o[0] = f2b(a.x); o[1] = f2b(a.y); o[2] = f2b(a.z); o[3] = f2b(a.w);
  o[4] = f2b(b.x); o[5] = f2b(b.y); o[6] = f2b(b.z); o[7] = f2b(b.w);
  *(bf16x8*)(dst + i) = o;
}

// rtok rows (per b: rows 256..511 of XC) f32 -> bf16 contiguous (B,256,C)
__global__ __launch_bounds__(256) void cvt_rtok(const float* __restrict__ xc,
                                                short* __restrict__ dst) {
  int i = blockIdx.x * 256 + threadIdx.x;  // short8 idx
  int b = i >> 15;
  int rem = i & 32767;
  const float* s = xc + (int64_t)b * 524288 + 262144 + (int64_t)rem * 8;
  float4 a = *(const float4*)s;
  float4 c = *(const float4*)(s + 4);
  bf16x8 o;
  o[0] = f2b(a.x); o[1] = f2b(a.y); o[2] = f2b(a.z); o[3] = f2b(a.w);
  o[4] = f2b(c.x); o[5] = f2b(c.y); o[6] = f2b(c.z); o[7] = f2b(c.w);
  *(bf16x8*)(dst + (int64_t)i * 8) = o;
}

// ---------------- wkv chunked parallel scan ----------------
__global__ __launch_bounds__(256) void wkv_p1(const float* __restrict__ td,
                                              const short* __restrict__ K,
                                              const short* __restrict__ V,
                                              float* __restrict__ Ca,
                                              float* __restrict__ Da,
                                              float* __restrict__ Qa) {
  int bx = blockIdx.x;  // [ch:5][b:3][cg:2]
  int ch = bx >> 5;
  int b = (bx >> 2) & 7;
  int c = (bx & 3) * 256 + threadIdx.x;
  float w = -expf(td[c]);
  float aa = 0.0f, bb = 0.0f, pp = -1e38f;
  int64_t base = ((int64_t)b * TT_ + ch * WKV_L) * TC_ + c;
#pragma unroll
  for (int t = 0; t < WKV_L; ++t) {
    int64_t o = base + (int64_t)t * TC_;
    float kt = b2f(K[o]), vt = b2f(V[o]);
    float ww2 = pp + w;
    float p2 = fmaxf(ww2, kt);
    float e1 = expf(ww2 - p2);
    float e2 = expf(kt - p2);
    aa = e1 * aa + e2 * vt;
    bb = e1 * bb + e2;
    pp = p2;
  }
  int idx = ch * 8192 + b * 1024 + c;
  Ca[idx] = aa; Da[idx] = bb; Qa[idx] = pp;
}

__global__ __launch_bounds__(256) void wkv_p2(const float* __restrict__ td,
                                              const float* __restrict__ Ca,
                                              const float* __restrict__ Da,
                                              const float* __restrict__ Qa,
                                              float* __restrict__ Aa,
                                              float* __restrict__ Ba,
                                              float* __restrict__ Pa) {
  int i = blockIdx.x * 256 + threadIdx.x;  // 0..8191 = b*1024+c
  int c = i & (TC_ - 1);
  float wL = -expf(td[c]) * (float)WKV_L;
  float aa = 0.0f, bb = 0.0f, pp = -1e38f;
#pragma unroll 4
  for (int ch = 0; ch < WKV_NCH; ++ch) {
    int idx = ch * 8192 + i;
    Aa[idx] = aa; Ba[idx] = bb; Pa[idx] = pp;
    float ppw = pp + wL;
    float q = Qa[idx];
    float p2 = fmaxf(ppw, q);
    float ea = expf(ppw - p2);
    float eb = expf(q - p2);
    aa = aa * ea + Ca[idx] * eb;
    bb = bb * ea + Da[idx] * eb;
    pp = p2;
  }
}

__global__ __launch_bounds__(256) void wkv_p3(const float* __restrict__ td,
                                              const float* __restrict__ tf,
                                              const short* __restrict__ K,
                                              const short* __restrict__ V,
                                              const short* __restrict__ SR,
                                              short* __restrict__ SRY,
                                              const float* __restrict__ Aa,
                                              const float* __restrict__ Ba,
                                              const float* __restrict__ Pa) {
  int bx = blockIdx.x;
  int ch = bx >> 5;
  int b = (bx >> 2) & 7;
  int c = (bx & 3) * 256 + threadIdx.x;
  float w = -expf(td[c]);
  float u = tf[c];
  int idx = ch * 8192 + b * 1024 + c;
  float aa = Aa[idx], bb = Ba[idx], pp = Pa[idx];
  int64_t base = ((int64_t)b * TT_ + ch * WKV_L) * TC_ + c;
#pragma unroll
  for (int t = 0; t < WKV_L; ++t) {
    int64_t o = base + (int64_t)t * TC_;
    float kt = b2f(K[o]), vt = b2f(V[o]);
    float ww = u + kt;
    float p = fmaxf(pp, ww);
    float E1 = expf(pp - p);
    float E2 = expf(ww - p);
    float y = (E1 * aa + E2 * vt) / (E1 * bb + E2);
    SRY[o] = f2b(y * b2f(SR[o]));
    float ww2 = pp + w;
    float p2 = fmaxf(ww2, kt);
    float e1 = expf(ww2 - p2);
    float e2 = expf(kt - p2);
    aa = e1 * aa + e2 * vt;
    bb = e1 * bb + e2;
    pp = p2;
  }
}

// S[c] = sum_j Wam[c][j] (j<256)
__global__ __launch_bounds__(64) void row_sum256(const float* __restrict__ Wam,
                                                 float* __restrict__ S) {
  int c = blockIdx.x;
  int lane = threadIdx.x;
  float4 v = ((const float4*)(Wam + (int64_t)c * 256))[lane];
  float s = v.x + v.y + v.z + v.w;
  for (int off = 32; off > 0; off >>= 1) s += __shfl_down(s, off);
  if (lane == 0) S[c] = s;
}

// ---------------- bf16 MFMA GEMM ----------------
// C[bz][m][n] = epi( sum_k A[m][k]*B[n][k] ), A: M x K bf16, B: N x K bf16.
// BM x BN tile, BK=32, 256 threads (4 waves 2x2). DEPTH=4 LDS ring buffer in
// MFMA lane order (0 bank conflicts) + counted-vmcnt pipeline: 3 tiles stay
// in flight across barriers (main-loop wait = vmcnt(3*NL), epilogue drains
// 2*NL -> NL -> 0). Per-wave protocol: wait own loads, then s_barrier.
// XCD chunked swizzle (bijective, requires nwg%8==0) for L2 panel reuse.
// EPI: 0 bf16; 1 sigmoid bf16; 2 relu^2 bf16;
//      3 tail-final f32 (e0=brm[m], e1=S[n], e2=bam[n], e3=XC f32, sE);
//      4 C(f32) += lif4(acc); 5 C(f32) += lif4(acc * e3[m][n] bf16);
//      6 z-select: bz==2 ? sigmoid : plain (bf16)
template <int BM, int BN, int EPI>
__global__ __launch_bounds__(256, 2) void gemm_bf16(
    const short* __restrict__ A, const short* __restrict__ B,
    void* __restrict__ Cp, int M, int N, int K,
    int64_t sA, int64_t sB, int64_t sC,
    const float* __restrict__ e0, const float* __restrict__ e1,
    const float* __restrict__ e2, const void* __restrict__ e3, int64_t sE) {
  constexpr int MF = BM / 32;      // m-frags per wave
  constexpr int NF = BN / 32;      // n-frags per wave
  constexpr int ASLOT = BM / 64;   // 16B stage slots per thread for A
  constexpr int BSLOT = BN / 64;
  constexpr int NL = ASLOT + BSLOT;     // loads per thread per tile
  constexpr int SBUF = (BM + BN) * 32;  // shorts per LDS buffer
  constexpr int D = 4;                  // pipeline depth
  __shared__ short lds[D * SBUF];
  const int tid = threadIdx.x;

  // bijective XCD chunked swizzle (m204): consecutive new-ids share an XCD
  const unsigned gx = gridDim.x, gy = gridDim.y;
  const unsigned nwg = gx * gy * gridDim.z;
  const unsigned lin = blockIdx.x + gx * (blockIdx.y + gy * blockIdx.z);
  const unsigned cs = nwg >> 3;
  const unsigned nl = (lin & 7) * cs + (lin >> 3);
  const unsigned bxs = nl % gx;
  const unsigned tmp = nl / gx;
  const unsigned bys = tmp % gy;
  const unsigned bz = tmp / gy;

  const int brow = bys * BM;
  const int bcol = bxs * BN;
  const short* Ab = A + bz * sA;
  const short* Bb = B + bz * sB;

  // lane-order staging: slot p -> row ((p>>6)<<4)+(p&15), k8 chunk (p>>4)&3
  const int srow = ((tid >> 6) << 4) + (tid & 15);
  const int skc = ((tid >> 4) & 3) * 8;
  const short* gA[ASLOT];
  const short* gB[BSLOT];
#pragma unroll
  for (int s = 0; s < ASLOT; ++s)
    gA[s] = Ab + (int64_t)(brow + s * 64 + srow) * K + skc;
#pragma unroll
  for (int s = 0; s < BSLOT; ++s)
    gB[s] = Bb + (int64_t)(bcol + s * 64 + srow) * K + skc;

  const int lane = tid & 63, wid = tid >> 6;
  const int wr = wid >> 1, wc = wid & 1;

  f32x4 acc[MF][NF] = {};

  auto stage = [&](int buf, int k0) {
    short* d = lds + buf * SBUF;
#pragma unroll
    for (int s = 0; s < ASLOT; ++s)
      gload16(gA[s] + k0, d + s * 2048 + tid * 8);
#pragma unroll
    for (int s = 0; s < BSLOT; ++s)
      gload16(gB[s] + k0, d + BM * 32 + s * 2048 + tid * 8);
  };
  auto compute = [&](int buf) {
    const short* base = lds + buf * SBUF;
    bf16x8 af[MF], bfv[NF];
#pragma unroll
    for (int m = 0; m < MF; ++m)
      af[m] = *(const bf16x8*)(base + (wr * MF + m) * 512 + lane * 8);
#pragma unroll
    for (int n = 0; n < NF; ++n)
      bfv[n] = *(const bf16x8*)(base + BM * 32 + (wc * NF + n) * 512 + lane * 8);
#pragma unroll
    for (int m = 0; m < MF; ++m)
#pragma unroll
      for (int n = 0; n < NF; ++n)
        acc[m][n] = __builtin_amdgcn_mfma_f32_16x16x32_bf16(af[m], bfv[n],
                                                            acc[m][n], 0, 0, 0);
  };

  const int nst = K / 32;  // >= D for all our shapes (min K=256 -> 8)
  // prologue: stage tiles 0..D-2
#pragma unroll
  for (int d = 0; d < D - 1; ++d) stage(d, d * 32);
  // main loop: keep D-1 tiles in flight
  for (int t = 0; t <= nst - D; ++t) {
    stage((t + D - 1) & (D - 1), (t + D - 1) * 32);
    waitv<(D - 1) * NL>();
    barrier_();            // all waves' tile-t loads resident
    compute(t & (D - 1));
    barrier_();            // reads done before buffer reuse next iter
  }
  // epilogue: drain the last D-1 tiles
  {
    int t = nst - D + 1;
    waitv<2 * NL>(); barrier_(); compute(t & (D - 1)); barrier_(); ++t;
    waitv<1 * NL>(); barrier_(); compute(t & (D - 1)); barrier_(); ++t;
    waitv<0>();      barrier_(); compute(t & (D - 1));
  }

  const int r0 = brow + wr * (BM / 2) + (lane >> 4) * 4;
  const int c0 = bcol + wc * (BN / 2) + (lane & 15);
#pragma unroll
  for (int m = 0; m < MF; ++m) {
#pragma unroll
    for (int j = 0; j < 4; ++j) {
      int row = r0 + m * 16 + j;
#pragma unroll
      for (int n = 0; n < NF; ++n) {
        int col = c0 + n * 16;
        float v = acc[m][n][j];
        int64_t idx = (int64_t)row * N + col;
        if (EPI == 0) {
          ((short*)Cp)[bz * sC + idx] = f2b(v);
        } else if (EPI == 1) {
          ((short*)Cp)[bz * sC + idx] = f2b(sigm(v));
        } else if (EPI == 2) {
          v = fmaxf(v, 0.0f);
          ((short*)Cp)[bz * sC + idx] = f2b(v * v);
        } else if (EPI == 3) {
          float r2 = v + e0[row] * e1[col] + e2[col];
          float xo = ((const float*)e3)[bz * sE + idx];
          ((float*)Cp)[bz * sC + idx] = xo * (1.0f + r2);
        } else if (EPI == 4) {
          float* XC = (float*)Cp;
          XC[idx] = XC[idx] + lif4(v);
        } else if (EPI == 5) {
          float* XC = (float*)Cp;
          float srr = b2f(((const short*)e3)[idx]);
          XC[idx] = XC[idx] + lif4(v * srr);
        } else if (EPI == 6) {
          ((short*)Cp)[bz * sC + idx] = f2b(bz == 2 ? sigm(v) : v);
        }
      }
    }
  }
}

// ---------------- launch ----------------
extern "C" void kernel_launch(void* const* d_in, const int* in_sizes, int n_in,
                              void* d_out, int out_size, void* d_ws,
                              size_t ws_size, hipStream_t stream) {
  const float* x   = (const float*)d_in[0];
  const float* rt  = (const float*)d_in[1];
  const float* td  = (const float*)d_in[2];
  const float* tf  = (const float*)d_in[3];
  const float* tmk = (const float*)d_in[4];
  const float* tmv = (const float*)d_in[5];
  const float* tmr = (const float*)d_in[6];
  const float* Wk  = (const float*)d_in[7];
  const float* Wv  = (const float*)d_in[8];
  const float* Wr  = (const float*)d_in[9];
  const float* Wo  = (const float*)d_in[10];
  const float* cmk = (const float*)d_in[11];
  const float* cmr = (const float*)d_in[12];
  const float* Wck = (const float*)d_in[13];
  const float* Wcv = (const float*)d_in[14];
  const float* Wcr = (const float*)d_in[15];
  const float* Wrm = (const float*)d_in[16];
  const float* brm = (const float*)d_in[17];
  const float* Wam = (const float*)d_in[18];
  const float* bam = (const float*)d_in[19];
  float* out = (float*)d_out;

  const size_t MB = 1ull << 20;
  uint8_t* W8 = (uint8_t*)d_ws;
  // Memory map (MB offsets), phase-ordered reuse:
  float* XC   = (float*)(W8);                        // 0-16 residual f32
  short* L    = (short*)(W8 + 16 * MB);              // 16-24 ln out
  short* S1   = (short*)(W8 + 24 * MB);              // 24-32 xk / SRY / SRR / Sb
  short* S2   = (short*)(W8 + 32 * MB);              // 32-40 xv / xk2 / rtok,Mt
  short* S3   = (short*)(W8 + 40 * MB);              // 40-48 xr / xr2 / bWck
  short* bWcv = (short*)(W8 + 48 * MB);              // 48-56
  short* bWk  = (short*)(W8 + 56 * MB);              // 56-62 bWk,bWv,bWr contig
  short* bWo  = (short*)(W8 + 62 * MB);
  short* bWcr = (short*)(W8 + 64 * MB);
  short* bWrm = (short*)(W8 + 66 * MB);              // 0.5 MB
  short* bWam = (short*)(W8 + 66 * MB + 512 * 1024); // 0.5 MB
  short* KK   = (short*)(W8 + 67 * MB);              // 67-75
  short* VV   = (short*)(W8 + 75 * MB);              // 75-83
  short* RR   = (short*)(W8 + 83 * MB);              // 83-91
  float* Ca   = (float*)(W8 + 91 * MB);
  float* Da   = (float*)(W8 + 92 * MB);
  float* Qa   = (float*)(W8 + 93 * MB);
  float* Aa   = (float*)(W8 + 94 * MB);
  float* Ba   = (float*)(W8 + 95 * MB);
  float* Pa   = (float*)(W8 + 96 * MB);
  short* SRY  = S1;
  short* xk2  = S2;
  short* xr2  = S3;
  short* SRR  = S1;
  short* bWck = S3;                                  // after SRR GEMM
  short* H16  = KK;                                  // 67-99 (32 MB)
  short* rtok = S2;                                  // 32-36
  short* Mt   = (short*)(W8 + 36 * MB);              // 36-37
  float* Sb   = (float*)(W8 + 24 * MB);              // 4 KB (SRR dead by then)

  dim3 blk(256);
  const int NV4 = 4096;   // B*T*C/4 / 256
  const int NV8 = 2048;   // B*T*C/8 / 256

  // weight conversions (time-mix + tail)
  cvt_b<<<512, blk, 0, stream>>>(Wk, bWk);
  cvt_b<<<512, blk, 0, stream>>>(Wv, bWk + 1048576);
  cvt_b<<<512, blk, 0, stream>>>(Wr, bWk + 2097152);
  cvt_b<<<512, blk, 0, stream>>>(Wo, bWo);
  cvt_b<<<512, blk, 0, stream>>>(Wcr, bWcr);
  cvt_b<<<128, blk, 0, stream>>>(Wrm, bWrm);
  cvt_b<<<128, blk, 0, stream>>>(Wam, bWam);

  // 1) xc = concat(x, rt); ln1 -> L; mixes -> S1,S2,S3
  build_xc<<<NV4, blk, 0, stream>>>(x, rt, XC);
  ln_rows_b<<<TB_ * TT_, blk, 0, stream>>>(XC, L);
  mix3_b<<<NV8, blk, 0, stream>>>(L, tmk, tmv, tmr, S1, S2, S3);

  // 2) fused z=3 time-mix GEMM: KK = xk*Wk^T, VV = xv*Wv^T, RR = sigm(xr*Wr^T)
  gemm_bf16<128, 128, 6><<<dim3(8, 32, 3), blk, 0, stream>>>(
      S1, bWk, KK, 4096, 1024, 1024, 4194304, 1048576, 4194304,
      nullptr, nullptr, nullptr, nullptr, 0);
  // 3) wkv chunked scan -> SRY (=S1)
  wkv_p1<<<WKV_NCH * TB_ * 4, blk, 0, stream>>>(td, KK, VV, Ca, Da, Qa);
  wkv_p2<<<32, blk, 0, stream>>>(td, Ca, Da, Qa, Aa, Ba, Pa);
  wkv_p3<<<WKV_NCH * TB_ * 4, blk, 0, stream>>>(td, tf, KK, VV, RR, SRY,
                                                Aa, Ba, Pa);
  // 4) att: XC += lif(SRY*Wo^T)
  gemm_bf16<128, 128, 4><<<dim3(8, 32, 1), blk, 0, stream>>>(
      SRY, bWo, XC, 4096, 1024, 1024, 0, 0, 0,
      nullptr, nullptr, nullptr, nullptr, 0);
  // 5) ln2 -> L; mix2 -> xk2(S2), xr2(S3)
  ln_rows_b<<<TB_ * TT_, blk, 0, stream>>>(XC, L);
  mix2_b<<<NV8, blk, 0, stream>>>(L, cmk, cmr, xk2, xr2);
  // 6) SRR = sigm(xr2*Wcr^T) -> S1
  gemm_bf16<128, 128, 1><<<dim3(8, 32, 1), blk, 0, stream>>>(
      xr2, bWcr, SRR, 4096, 1024, 1024, 0, 0, 0,
      nullptr, nullptr, nullptr, nullptr, 0);
  // 7) channel-mix weights into dead regions (xr2 slot, bWcv slot)
  cvt_b<<<2048, blk, 0, stream>>>(Wck, bWck);
  cvt_b<<<2048, blk, 0, stream>>>(Wcv, bWcv);
  // 8) H = relu^2(xk2*Wck^T) -> H16 (4096x4096)
  gemm_bf16<128, 128, 2><<<dim3(32, 32, 1), blk, 0, stream>>>(
      xk2, bWck, H16, 4096, 4096, 1024, 0, 0, 0,
      nullptr, nullptr, nullptr, nullptr, 0);
  // 9) XC += lif(SRR * (H*Wcv^T))
  gemm_bf16<128, 128, 5><<<dim3(8, 32, 1), blk, 0, stream>>>(
      H16, bWcv, XC, 4096, 1024, 4096, 0, 0, 0,
      nullptr, nullptr, nullptr, SRR, 0);
  // 10) tail
  cvt_rtok<<<1024, blk, 0, stream>>>(XC, rtok);
  gemm_bf16<64, 64, 0><<<dim3(4, 4, 8), blk, 0, stream>>>(
      bWrm, rtok, Mt, 256, 256, 1024, 0, (int64_t)256 * 1024,
      (int64_t)256 * 256, nullptr, nullptr, nullptr, nullptr, 0);
  row_sum256<<<1024, dim3(64), 0, stream>>>(Wam, Sb);
  gemm_bf16<64, 64, 3><<<dim3(16, 4, 8), blk, 0, stream>>>(
      Mt, bWam, out, 256, 1024, 256, (int64_t)256 * 256, 0,
      (int64_t)256 * 1024, brm, Sb, bam, XC, (int64_t)512 * 1024);
}

// Round 8
// 355.280 us; speedup vs baseline: 1.2431x; 1.0016x over previous
//
#include <hip/hip_runtime.h>
#include <hip/hip_bf16.h>
#include <math.h>
#include <stdint.h>

// B=8, P1=256 -> T=512 concat rows, C=1024, H=4096
#define TB_ 8
#define TT_ 512
#define TC_ 1024
// wkv chunked scan: 32 chunks of 16 steps
#define WKV_NCH 32
#define WKV_L 16

typedef __attribute__((ext_vector_type(8))) short bf16x8;
typedef __attribute__((ext_vector_type(4))) short s16x4;
typedef __attribute__((ext_vector_type(4))) float f32x4;

__device__ __forceinline__ float b2f(short u) {
  union { unsigned int i; float f; } x;
  x.i = ((unsigned int)(unsigned short)u) << 16;
  return x.f;
}
__device__ __forceinline__ short f2b(float f) {
  __hip_bfloat16 h = __float2bfloat16(f);  // RNE
  return __builtin_bit_cast(short, h);
}
__device__ __forceinline__ float sigm(float x) { return 1.0f / (1.0f + expf(-x)); }

// LIF over 4 identical inputs (closed form of the reference scan), TAU=2, VTH=1
__device__ __forceinline__ float lif4(float a) {
  float v = 0.0f, acc = 0.0f;
#pragma unroll
  for (int i = 0; i < 4; ++i) {
    v += (a - v) * 0.5f;
    float s = (v >= 1.0f) ? 1.0f : 0.0f;
    acc += s;
    v *= (1.0f - s);
  }
  return acc * 0.25f;
}

__device__ __forceinline__ void gload16(const void* g, void* l) {
  __builtin_amdgcn_global_load_lds(
      (__attribute__((address_space(1))) void*)(g),
      (__attribute__((address_space(3))) void*)(l), 16, 0, 0);
}

// counted vmcnt wait (compile-time immediate)
template <int N>
__device__ __forceinline__ void waitv() {
  if constexpr (N == 0)  asm volatile("s_waitcnt vmcnt(0)" ::: "memory");
  else if constexpr (N == 2)  asm volatile("s_waitcnt vmcnt(2)" ::: "memory");
  else if constexpr (N == 4)  asm volatile("s_waitcnt vmcnt(4)" ::: "memory");
  else if constexpr (N == 6)  asm volatile("s_waitcnt vmcnt(6)" ::: "memory");
  else if constexpr (N == 8)  asm volatile("s_waitcnt vmcnt(8)" ::: "memory");
  else if constexpr (N == 12) asm volatile("s_waitcnt vmcnt(12)" ::: "memory");
  else if constexpr (N == 16) asm volatile("s_waitcnt vmcnt(16)" ::: "memory");
  else if constexpr (N == 20) asm volatile("s_waitcnt vmcnt(20)" ::: "memory");
  else if constexpr (N == 24) asm volatile("s_waitcnt vmcnt(24)" ::: "memory");
  else if constexpr (N == 28) asm volatile("s_waitcnt vmcnt(28)" ::: "memory");
  else static_assert(N == 0, "unsupported vmcnt");
}
__device__ __forceinline__ void barrier_() {
  asm volatile("s_barrier" ::: "memory");
}

// ---------------- elementwise kernels ----------------

// fused concat + LayerNorm: row of xc = (t<256 ? x : rt); writes XC (f32 copy)
// and LN output (bf16). One 256-thread block per row (4096 rows).
__global__ __launch_bounds__(256) void ln_first(const float* __restrict__ x,
                                                const float* __restrict__ rt,
                                                float* __restrict__ xc,
                                                short* __restrict__ dst) {
  __shared__ float red[256];
  int row = blockIdx.x;  // b*512 + t
  int t = row & 511, b = row >> 9;
  const float* src = (t < 256) ? x + (int64_t)(b * 256 + t) * TC_
                               : rt + (int64_t)(t - 256) * TC_;
  float4 v = ((const float4*)src)[threadIdx.x];
  ((float4*)(xc + (int64_t)row * TC_))[threadIdx.x] = v;
  red[threadIdx.x] = v.x + v.y + v.z + v.w;
  __syncthreads();
  for (int off = 128; off > 0; off >>= 1) {
    if (threadIdx.x < off) red[threadIdx.x] += red[threadIdx.x + off];
    __syncthreads();
  }
  float mean = red[0] * (1.0f / 1024.0f);
  __syncthreads();
  float dx = v.x - mean, dy = v.y - mean, dz = v.z - mean, dw = v.w - mean;
  red[threadIdx.x] = dx * dx + dy * dy + dz * dz + dw * dw;
  __syncthreads();
  for (int off = 128; off > 0; off >>= 1) {
    if (threadIdx.x < off) red[threadIdx.x] += red[threadIdx.x + off];
    __syncthreads();
  }
  float rs = 1.0f / sqrtf(red[0] * (1.0f / 1024.0f) + 1e-6f);
  s16x4 o;
  o.x = f2b(dx * rs); o.y = f2b(dy * rs); o.z = f2b(dz * rs); o.w = f2b(dw * rs);
  *(s16x4*)(dst + (int64_t)row * TC_ + threadIdx.x * 4) = o;
}

// LayerNorm each row (C=1024 f32) -> bf16. One 256-thread block per row.
__global__ __launch_bounds__(256) void ln_rows_b(const float* __restrict__ src,
                                                 short* __restrict__ dst) {
  __shared__ float red[256];
  int64_t row = blockIdx.x;
  float4 v = ((const float4*)(src + row * TC_))[threadIdx.x];
  red[threadIdx.x] = v.x + v.y + v.z + v.w;
  __syncthreads();
  for (int off = 128; off > 0; off >>= 1) {
    if (threadIdx.x < off) red[threadIdx.x] += red[threadIdx.x + off];
    __syncthreads();
  }
  float mean = red[0] * (1.0f / 1024.0f);
  __syncthreads();
  float dx = v.x - mean, dy = v.y - mean, dz = v.z - mean, dw = v.w - mean;
  red[threadIdx.x] = dx * dx + dy * dy + dz * dz + dw * dw;
  __syncthreads();
  for (int off = 128; off > 0; off >>= 1) {
    if (threadIdx.x < off) red[threadIdx.x] += red[threadIdx.x + off];
    __syncthreads();
  }
  float rs = 1.0f / sqrtf(red[0] * (1.0f / 1024.0f) + 1e-6f);
  s16x4 o;
  o.x = f2b(dx * rs); o.y = f2b(dy * rs); o.z = f2b(dz * rs); o.w = f2b(dw * rs);
  *(s16x4*)(dst + row * TC_ + threadIdx.x * 4) = o;
}

// time-mix blends from bf16 LN. 8 elems/thread; i over B*T*C/8.
__global__ __launch_bounds__(256) void mix3_b(const short* __restrict__ ln,
                                              const float* __restrict__ tk,
                                              const float* __restrict__ tv,
                                              const float* __restrict__ tr,
                                              short* __restrict__ xk,
                                              short* __restrict__ xv,
                                              short* __restrict__ xr) {
  int i = blockIdx.x * 256 + threadIdx.x;  // short8 index
  int c8 = i & 127;
  int t = (i >> 7) & 511;
  bf16x8 h = *(const bf16x8*)(ln + (int64_t)i * 8);
  bf16x8 s = {};
  if (t > 0) s = *(const bf16x8*)(ln + (int64_t)(i - 128) * 8);
  bf16x8 ok, ov, orr;
#pragma unroll
  for (int e = 0; e < 8; ++e) {
    float hf = b2f(h[e]), sf = b2f(s[e]);
    int c = c8 * 8 + e;
    float mk = tk[c], mv = tv[c], mr = tr[c];
    ok[e] = f2b(hf * mk + sf * (1.0f - mk));
    ov[e] = f2b(hf * mv + sf * (1.0f - mv));
    orr[e] = f2b(hf * mr + sf * (1.0f - mr));
  }
  *(bf16x8*)(xk + (int64_t)i * 8) = ok;
  *(bf16x8*)(xv + (int64_t)i * 8) = ov;
  *(bf16x8*)(xr + (int64_t)i * 8) = orr;
}

__global__ __launch_bounds__(256) void mix2_b(const short* __restrict__ ln,
                                              const float* __restrict__ tk,
                                              const float* __restrict__ tr,
                                              short* __restrict__ xk,
                                              short* __restrict__ xr) {
  int i = blockIdx.x * 256 + threadIdx.x;
  int c8 = i & 127;
  int t = (i >> 7) & 511;
  bf16x8 h = *(const bf16x8*)(ln + (int64_t)i * 8);
  bf16x8 s = {};
  if (t > 0) s = *(const bf16x8*)(ln + (int64_t)(i - 128) * 8);
  bf16x8 ok, orr;
#pragma unroll
  for (int e = 0; e < 8; ++e) {
    float hf = b2f(h[e]), sf = b2f(s[e]);
    int c = c8 * 8 + e;
    float mk = tk[c], mr = tr[c];
    ok[e] = f2b(hf * mk + sf * (1.0f - mk));
    orr[e] = f2b(hf * mr + sf * (1.0f - mr));
  }
  *(bf16x8*)(xk + (int64_t)i * 8) = ok;
  *(bf16x8*)(xr + (int64_t)i * 8) = orr;
}

// f32 -> bf16, 8 elems/thread
__global__ __launch_bounds__(256) void cvt_b(const float* __restrict__ src,
                                             short* __restrict__ dst) {
  int64_t i = (int64_t)(blockIdx.x * 256 + threadIdx.x) * 8;
  float4 a = *(const float4*)(src + i);
  float4 b = *(const float4*)(src + i + 4);
  bf16x8 o;
  o[0] = f2b(a.x); o[1] = f2b(a.y); o[2] = f2b(a.z); o[3] = f2b(a.w);
  o[4] = f2b(b.x); o[5] = f2b(b.y); o[6] = f2b(b.z); o[7] = f2b(b.w);
  *(bf16x8*)(dst + i) = o;
}

// rtok rows (per b: rows 256..511 of XC) f32 -> bf16 contiguous (B,256,C)
__global__ __launch_bounds__(256) void cvt_rtok(const float* __restrict__ xc,
                                                short* __restrict__ dst) {
  int i = blockIdx.x * 256 + threadIdx.x;  // short8 idx
  int b = i >> 15;
  int rem = i & 32767;
  const float* s = xc + (int64_t)b * 524288 + 262144 + (int64_t)rem * 8;
  float4 a = *(const float4*)s;
  float4 c = *(const float4*)(s + 4);
  bf16x8 o;
  o[0] = f2b(a.x); o[1] = f2b(a.y); o[2] = f2b(a.z); o[3] = f2b(a.w);
  o[4] = f2b(c.x); o[5] = f2b(c.y); o[6] = f2b(c.z); o[7] = f2b(c.w);
  *(bf16x8*)(dst + (int64_t)i * 8) = o;
}

// ---------------- wkv chunked parallel scan ----------------
__global__ __launch_bounds__(256) void wkv_p1(const float* __restrict__ td,
                                              const short* __restrict__ K,
                                              const short* __restrict__ V,
                                              float* __restrict__ Ca,
                                              float* __restrict__ Da,
                                              float* __restrict__ Qa) {
  int bx = blockIdx.x;  // [ch:5][b:3][cg:2]
  int ch = bx >> 5;
  int b = (bx >> 2) & 7;
  int c = (bx & 3) * 256 + threadIdx.x;
  float w = -expf(td[c]);
  float aa = 0.0f, bb = 0.0f, pp = -1e38f;
  int64_t base = ((int64_t)b * TT_ + ch * WKV_L) * TC_ + c;
#pragma unroll
  for (int t = 0; t < WKV_L; ++t) {
    int64_t o = base + (int64_t)t * TC_;
    float kt = b2f(K[o]), vt = b2f(V[o]);
    float ww2 = pp + w;
    float p2 = fmaxf(ww2, kt);
    float e1 = expf(ww2 - p2);
    float e2 = expf(kt - p2);
    aa = e1 * aa + e2 * vt;
    bb = e1 * bb + e2;
    pp = p2;
  }
  int idx = ch * 8192 + b * 1024 + c;
  Ca[idx] = aa; Da[idx] = bb; Qa[idx] = pp;
}

__global__ __launch_bounds__(256) void wkv_p2(const float* __restrict__ td,
                                              const float* __restrict__ Ca,
                                              const float* __restrict__ Da,
                                              const float* __restrict__ Qa,
                                              float* __restrict__ Aa,
                                              float* __restrict__ Ba,
                                              float* __restrict__ Pa) {
  int i = blockIdx.x * 256 + threadIdx.x;  // 0..8191 = b*1024+c
  int c = i & (TC_ - 1);
  float wL = -expf(td[c]) * (float)WKV_L;
  float aa = 0.0f, bb = 0.0f, pp = -1e38f;
#pragma unroll 4
  for (int ch = 0; ch < WKV_NCH; ++ch) {
    int idx = ch * 8192 + i;
    Aa[idx] = aa; Ba[idx] = bb; Pa[idx] = pp;
    float ppw = pp + wL;
    float q = Qa[idx];
    float p2 = fmaxf(ppw, q);
    float ea = expf(ppw - p2);
    float eb = expf(q - p2);
    aa = aa * ea + Ca[idx] * eb;
    bb = bb * ea + Da[idx] * eb;
    pp = p2;
  }
}

__global__ __launch_bounds__(256) void wkv_p3(const float* __restrict__ td,
                                              const float* __restrict__ tf,
                                              const short* __restrict__ K,
                                              const short* __restrict__ V,
                                              const short* __restrict__ SR,
                                              short* __restrict__ SRY,
                                              const float* __restrict__ Aa,
                                              const float* __restrict__ Ba,
                                              const float* __restrict__ Pa) {
  int bx = blockIdx.x;
  int ch = bx >> 5;
  int b = (bx >> 2) & 7;
  int c = (bx & 3) * 256 + threadIdx.x;
  float w = -expf(td[c]);
  float u = tf[c];
  int idx = ch * 8192 + b * 1024 + c;
  float aa = Aa[idx], bb = Ba[idx], pp = Pa[idx];
  int64_t base = ((int64_t)b * TT_ + ch * WKV_L) * TC_ + c;
#pragma unroll
  for (int t = 0; t < WKV_L; ++t) {
    int64_t o = base + (int64_t)t * TC_;
    float kt = b2f(K[o]), vt = b2f(V[o]);
    float ww = u + kt;
    float p = fmaxf(pp, ww);
    float E1 = expf(pp - p);
    float E2 = expf(ww - p);
    float y = (E1 * aa + E2 * vt) / (E1 * bb + E2);
    SRY[o] = f2b(y * b2f(SR[o]));
    float ww2 = pp + w;
    float p2 = fmaxf(ww2, kt);
    float e1 = expf(ww2 - p2);
    float e2 = expf(kt - p2);
    aa = e1 * aa + e2 * vt;
    bb = e1 * bb + e2;
    pp = p2;
  }
}

// S[c] = sum_j Wam[c][j] (j<256)
__global__ __launch_bounds__(64) void row_sum256(const float* __restrict__ Wam,
                                                 float* __restrict__ S) {
  int c = blockIdx.x;
  int lane = threadIdx.x;
  float4 v = ((const float4*)(Wam + (int64_t)c * 256))[lane];
  float s = v.x + v.y + v.z + v.w;
  for (int off = 32; off > 0; off >>= 1) s += __shfl_down(s, off);
  if (lane == 0) S[c] = s;
}

// ---------------- bf16 MFMA GEMM ----------------
// C[bz][m][n] = epi( sum_k A[m][k]*B[n][k] ), A: M x K bf16, B: N x K bf16.
// BM x BN tile, BK=32, 256 threads (4 waves 2x2). Depth-D LDS ring buffer in
// MFMA lane order (0 bank conflicts) + counted-vmcnt pipeline: D-1 tiles stay
// in flight across barriers. D=8 for 1-block/CU grids (max in-flight bytes);
// D=2 for >=3-block/CU grids (LDS small so blocks co-reside -> TLP overlap).
// XCD chunked swizzle (bijective, requires nwg%8==0) for L2 panel reuse.
// EPI: 0 bf16; 1 sigmoid bf16; 2 relu^2 bf16;
//      3 tail-final f32 (e0=brm[m], e1=S[n], e2=bam[n], e3=XC f32, sE);
//      4 C(f32) += lif4(acc); 5 C(f32) += lif4(acc * e3[m][n] bf16);
//      6 z-select: bz==2 ? sigmoid : plain (bf16)
template <int BM, int BN, int EPI, int D, int MINW>
__global__ __launch_bounds__(256, MINW) void gemm_bf16(
    const short* __restrict__ A, const short* __restrict__ B,
    void* __restrict__ Cp, int M, int N, int K,
    int64_t sA, int64_t sB, int64_t sC,
    const float* __restrict__ e0, const float* __restrict__ e1,
    const float* __restrict__ e2, const void* __restrict__ e3, int64_t sE) {
  constexpr int MF = BM / 32;      // m-frags per wave
  constexpr int NF = BN / 32;      // n-frags per wave
  constexpr int ASLOT = BM / 64;   // 16B stage slots per thread for A
  constexpr int BSLOT = BN / 64;
  constexpr int NL = ASLOT + BSLOT;     // loads per thread per tile
  constexpr int SBUF = (BM + BN) * 32;  // shorts per LDS buffer
  __shared__ short lds[D * SBUF];
  const int tid = threadIdx.x;

  // bijective XCD chunked swizzle (m204): consecutive new-ids share an XCD
  const unsigned gx = gridDim.x, gy = gridDim.y;
  const unsigned nwg = gx * gy * gridDim.z;
  const unsigned lin = blockIdx.x + gx * (blockIdx.y + gy * blockIdx.z);
  const unsigned cs = nwg >> 3;
  const unsigned nl = (lin & 7) * cs + (lin >> 3);
  const unsigned bxs = nl % gx;
  const unsigned tmp = nl / gx;
  const unsigned bys = tmp % gy;
  const unsigned bz = tmp / gy;

  const int brow = bys * BM;
  const int bcol = bxs * BN;
  const short* Ab = A + bz * sA;
  const short* Bb = B + bz * sB;

  // lane-order staging: slot p -> row ((p>>6)<<4)+(p&15), k8 chunk (p>>4)&3
  const int srow = ((tid >> 6) << 4) + (tid & 15);
  const int skc = ((tid >> 4) & 3) * 8;
  const short* gA[ASLOT];
  const short* gB[BSLOT];
#pragma unroll
  for (int s = 0; s < ASLOT; ++s)
    gA[s] = Ab + (int64_t)(brow + s * 64 + srow) * K + skc;
#pragma unroll
  for (int s = 0; s < BSLOT; ++s)
    gB[s] = Bb + (int64_t)(bcol + s * 64 + srow) * K + skc;

  const int lane = tid & 63, wid = tid >> 6;
  const int wr = wid >> 1, wc = wid & 1;

  f32x4 acc[MF][NF] = {};

  auto stage = [&](int buf, int k0) {
    short* d = lds + buf * SBUF;
#pragma unroll
    for (int s = 0; s < ASLOT; ++s)
      gload16(gA[s] + k0, d + s * 2048 + tid * 8);
#pragma unroll
    for (int s = 0; s < BSLOT; ++s)
      gload16(gB[s] + k0, d + BM * 32 + s * 2048 + tid * 8);
  };
  auto compute = [&](int buf) {
    const short* base = lds + buf * SBUF;
    bf16x8 af[MF], bfv[NF];
#pragma unroll
    for (int m = 0; m < MF; ++m)
      af[m] = *(const bf16x8*)(base + (wr * MF + m) * 512 + lane * 8);
#pragma unroll
    for (int n = 0; n < NF; ++n)
      bfv[n] = *(const bf16x8*)(base + BM * 32 + (wc * NF + n) * 512 + lane * 8);
#pragma unroll
    for (int m = 0; m < MF; ++m)
#pragma unroll
      for (int n = 0; n < NF; ++n)
        acc[m][n] = __builtin_amdgcn_mfma_f32_16x16x32_bf16(af[m], bfv[n],
                                                            acc[m][n], 0, 0, 0);
  };

  const int nst = K / 32;  // >= D for all instantiations used
  // prologue: stage tiles 0..D-2
#pragma unroll
  for (int d = 0; d < D - 1; ++d) stage(d, d * 32);
  // main loop: keep D-1 tiles in flight
  for (int t = 0; t <= nst - D; ++t) {
    stage((t + D - 1) & (D - 1), (t + D - 1) * 32);
    waitv<(D - 1) * NL>();
    barrier_();            // all waves' tile-t loads resident
    compute(t & (D - 1));
    barrier_();            // reads done before buffer reuse next iter
  }
  // epilogue: drain the last D-1 tiles
  {
    int t = nst - D + 1;
    if constexpr (D >= 8) {
      waitv<6 * NL>(); barrier_(); compute(t & (D - 1)); barrier_(); ++t;
      waitv<5 * NL>(); barrier_(); compute(t & (D - 1)); barrier_(); ++t;
      waitv<4 * NL>(); barrier_(); compute(t & (D - 1)); barrier_(); ++t;
      waitv<3 * NL>(); barrier_(); compute(t & (D - 1)); barrier_(); ++t;
    }
    if constexpr (D >= 4) {
      waitv<2 * NL>(); barrier_(); compute(t & (D - 1)); barrier_(); ++t;
      waitv<1 * NL>(); barrier_(); compute(t & (D - 1)); barrier_(); ++t;
    }
    waitv<0>(); barrier_(); compute(t & (D - 1));
  }

  const int r0 = brow + wr * (BM / 2) + (lane >> 4) * 4;
  const int c0 = bcol + wc * (BN / 2) + (lane & 15);
#pragma unroll
  for (int m = 0; m < MF; ++m) {
#pragma unroll
    for (int j = 0; j < 4; ++j) {
      int row = r0 + m * 16 + j;
#pragma unroll
      for (int n = 0; n < NF; ++n) {
        int col = c0 + n * 16;
        float v = acc[m][n][j];
        int64_t idx = (int64_t)row * N + col;
        if (EPI == 0) {
          ((short*)Cp)[bz * sC + idx] = f2b(v);
        } else if (EPI == 1) {
          ((short*)Cp)[bz * sC + idx] = f2b(sigm(v));
        } else if (EPI == 2) {
          v = fmaxf(v, 0.0f);
          ((short*)Cp)[bz * sC + idx] = f2b(v * v);
        } else if (EPI == 3) {
          float r2 = v + e0[row] * e1[col] + e2[col];
          float xo = ((const float*)e3)[bz * sE + idx];
          ((float*)Cp)[bz * sC + idx] = xo * (1.0f + r2);
        } else if (EPI == 4) {
          float* XC = (float*)Cp;
          XC[idx] = XC[idx] + lif4(v);
        } else if (EPI == 5) {
          float* XC = (float*)Cp;
          float srr = b2f(((const short*)e3)[idx]);
          XC[idx] = XC[idx] + lif4(v * srr);
        } else if (EPI == 6) {
          ((short*)Cp)[bz * sC + idx] = f2b(bz == 2 ? sigm(v) : v);
        }
      }
    }
  }
}

// ---------------- launch ----------------
extern "C" void kernel_launch(void* const* d_in, const int* in_sizes, int n_in,
                              void* d_out, int out_size, void* d_ws,
                              size_t ws_size, hipStream_t stream) {
  const float* x   = (const float*)d_in[0];
  const float* rt  = (const float*)d_in[1];
  const float* td  = (const float*)d_in[2];
  const float* tf  = (const float*)d_in[3];
  const float* tmk = (const float*)d_in[4];
  const float* tmv = (const float*)d_in[5];
  const float* tmr = (const float*)d_in[6];
  const float* Wk  = (const float*)d_in[7];
  const float* Wv  = (const float*)d_in[8];
  const float* Wr  = (const float*)d_in[9];
  const float* Wo  = (const float*)d_in[10];
  const float* cmk = (const float*)d_in[11];
  const float* cmr = (const float*)d_in[12];
  const float* Wck = (const float*)d_in[13];
  const float* Wcv = (const float*)d_in[14];
  const float* Wcr = (const float*)d_in[15];
  const float* Wrm = (const float*)d_in[16];
  const float* brm = (const float*)d_in[17];
  const float* Wam = (const float*)d_in[18];
  const float* bam = (const float*)d_in[19];
  float* out = (float*)d_out;

  const size_t MB = 1ull << 20;
  uint8_t* W8 = (uint8_t*)d_ws;
  // Memory map (MB offsets), phase-ordered reuse:
  float* XC   = (float*)(W8);                        // 0-16 residual f32
  short* L    = (short*)(W8 + 16 * MB);              // 16-24 ln out
  short* S1   = (short*)(W8 + 24 * MB);              // 24-32 xk / SRY / SRR / Sb
  short* S2   = (short*)(W8 + 32 * MB);              // 32-40 xv / xk2 / rtok,Mt
  short* S3   = (short*)(W8 + 40 * MB);              // 40-48 xr / xr2 / bWck
  short* bWcv = (short*)(W8 + 48 * MB);              // 48-56
  short* bWk  = (short*)(W8 + 56 * MB);              // 56-62 bWk,bWv,bWr contig
  short* bWo  = (short*)(W8 + 62 * MB);
  short* bWcr = (short*)(W8 + 64 * MB);
  short* bWrm = (short*)(W8 + 66 * MB);              // 0.5 MB
  short* bWam = (short*)(W8 + 66 * MB + 512 * 1024); // 0.5 MB
  short* KK   = (short*)(W8 + 67 * MB);              // 67-75
  short* VV   = (short*)(W8 + 75 * MB);              // 75-83
  short* RR   = (short*)(W8 + 83 * MB);              // 83-91
  float* Ca   = (float*)(W8 + 91 * MB);
  float* Da   = (float*)(W8 + 92 * MB);
  float* Qa   = (float*)(W8 + 93 * MB);
  float* Aa   = (float*)(W8 + 94 * MB);
  float* Ba   = (float*)(W8 + 95 * MB);
  float* Pa   = (float*)(W8 + 96 * MB);
  short* SRY  = S1;
  short* xk2  = S2;
  short* xr2  = S3;
  short* SRR  = S1;
  short* bWck = S3;                                  // after SRR GEMM
  short* H16  = KK;                                  // 67-99 (32 MB)
  short* rtok = S2;                                  // 32-36
  short* Mt   = (short*)(W8 + 36 * MB);              // 36-37
  float* Sb   = (float*)(W8 + 24 * MB);              // 4 KB (SRR dead by then)

  dim3 blk(256);
  const int NV8 = 2048;   // B*T*C/8 / 256

  // weight conversions (time-mix + tail)
  cvt_b<<<512, blk, 0, stream>>>(Wk, bWk);
  cvt_b<<<512, blk, 0, stream>>>(Wv, bWk + 1048576);
  cvt_b<<<512, blk, 0, stream>>>(Wr, bWk + 2097152);
  cvt_b<<<512, blk, 0, stream>>>(Wo, bWo);
  cvt_b<<<512, blk, 0, stream>>>(Wcr, bWcr);
  cvt_b<<<128, blk, 0, stream>>>(Wrm, bWrm);
  cvt_b<<<128, blk, 0, stream>>>(Wam, bWam);

  // 1) fused concat+ln1 -> XC, L; mixes -> S1,S2,S3
  ln_first<<<TB_ * TT_, blk, 0, stream>>>(x, rt, XC, L);
  mix3_b<<<NV8, blk, 0, stream>>>(L, tmk, tmv, tmr, S1, S2, S3);

  // 2) fused z=3 time-mix GEMM: KK = xk*Wk^T, VV = xv*Wv^T, RR = sigm(xr*Wr^T)
  gemm_bf16<128, 128, 6, 2, 3><<<dim3(8, 32, 3), blk, 0, stream>>>(
      S1, bWk, KK, 4096, 1024, 1024, 4194304, 1048576, 4194304,
      nullptr, nullptr, nullptr, nullptr, 0);
  // 3) wkv chunked scan -> SRY (=S1)
  wkv_p1<<<WKV_NCH * TB_ * 4, blk, 0, stream>>>(td, KK, VV, Ca, Da, Qa);
  wkv_p2<<<32, blk, 0, stream>>>(td, Ca, Da, Qa, Aa, Ba, Pa);
  wkv_p3<<<WKV_NCH * TB_ * 4, blk, 0, stream>>>(td, tf, KK, VV, RR, SRY,
                                                Aa, Ba, Pa);
  // 4) att: XC += lif(SRY*Wo^T)   (grid 256 = 1 blk/CU -> D=8 deep pipeline)
  gemm_bf16<128, 128, 4, 8, 1><<<dim3(8, 32, 1), blk, 0, stream>>>(
      SRY, bWo, XC, 4096, 1024, 1024, 0, 0, 0,
      nullptr, nullptr, nullptr, nullptr, 0);
  // 5) ln2 -> L; mix2 -> xk2(S2), xr2(S3)
  ln_rows_b<<<TB_ * TT_, blk, 0, stream>>>(XC, L);
  mix2_b<<<NV8, blk, 0, stream>>>(L, cmk, cmr, xk2, xr2);
  // 6) SRR = sigm(xr2*Wcr^T) -> S1
  gemm_bf16<128, 128, 1, 8, 1><<<dim3(8, 32, 1), blk, 0, stream>>>(
      xr2, bWcr, SRR, 4096, 1024, 1024, 0, 0, 0,
      nullptr, nullptr, nullptr, nullptr, 0);
  // 7) channel-mix weights into dead regions (xr2 slot, bWcv slot)
  cvt_b<<<2048, blk, 0, stream>>>(Wck, bWck);
  cvt_b<<<2048, blk, 0, stream>>>(Wcv, bWcv);
  // 8) H = relu^2(xk2*Wck^T) -> H16 (grid 1024 = 4 blk/CU -> D=2 + co-res)
  gemm_bf16<128, 128, 2, 2, 4><<<dim3(32, 32, 1), blk, 0, stream>>>(
      xk2, bWck, H16, 4096, 4096, 1024, 0, 0, 0,
      nullptr, nullptr, nullptr, nullptr, 0);
  // 9) XC += lif(SRR * (H*Wcv^T))  (grid 256 -> D=8)
  gemm_bf16<128, 128, 5, 8, 1><<<dim3(8, 32, 1), blk, 0, stream>>>(
      H16, bWcv, XC, 4096, 1024, 4096, 0, 0, 0,
      nullptr, nullptr, nullptr, SRR, 0);
  // 10) tail
  cvt_rtok<<<1024, blk, 0, stream>>>(XC, rtok);
  gemm_bf16<64, 64, 0, 2, 2><<<dim3(4, 4, 8), blk, 0, stream>>>(
      bWrm, rtok, Mt, 256, 256, 1024, 0, (int64_t)256 * 1024,
      (int64_t)256 * 256, nullptr, nullptr, nullptr, nullptr, 0);
  row_sum256<<<1024, dim3(64), 0, stream>>>(Wam, Sb);
  gemm_bf16<64, 64, 3, 2, 2><<<dim3(16, 4, 8), blk, 0, stream>>>(
      Mt, bWam, out, 256, 1024, 256, (int64_t)256 * 256, 0,
      (int64_t)256 * 1024, brm, Sb, bam, XC, (int64_t)512 * 1024);
}